// Round 9
// baseline (4771.789 us; speedup 1.0000x reference)
//
#include <hip/hip_runtime.h>
#include <cstdint>
#include <cstddef>

using bf16 = __bf16;
typedef float f32x4 __attribute__((ext_vector_type(4)));
typedef bf16 bf16x8 __attribute__((ext_vector_type(8)));
typedef bf16 bf16x4 __attribute__((ext_vector_type(4)));

#define NB 4           // batch
#define SEQ 2048
#define DM 1024        // d_model
#define HD 4096        // hidden
#define SD (SEQ*DM)    // 2^21 elems per sample

__device__ __forceinline__ float geluf(float v) {
    return 0.5f * v * (1.0f + erff(v * 0.70710678118654752f));
}

#define GLL(gp, lp) __builtin_amdgcn_global_load_lds( \
    (const __attribute__((address_space(1))) void*)(gp), \
    (__attribute__((address_space(3))) void*)(lp), 16, 0, 0)

// ---------------------------------------------------------------------------
// Split-precision NT GEMM, fused NP-pass, double-buffered LDS with counted
// vmcnt prefetch (T3/T4-lite):
//   NP=3: C = Ah*Bh + Al*Bh + Ah*Bl  (~17-bit mantissa, f32 accum)
//   NP=1: C = Ah*Bh                  (plain bf16)
// A: M x K row-major bf16 (pair), Bt: N x K row-major bf16 (pair).
// Tile 128x128x64, 4 waves, 16x16x32 bf16 MFMA. Pipeline per K-step:
//   STAGE(next buf) ; s_waitcnt vmcnt(16|8)  [prev tile landed, next in
//   flight ACROSS the barrier] ; s_barrier ; ds_read+MFMA(cur) ; s_barrier.
// Raw s_barrier (not __syncthreads) so the counted vmcnt survives; lgkm is
// drained naturally by MFMA consumption before the trailing barrier.
// Chunk XOR swizzle (c' = c ^ (m&7)) on BOTH global source and ds_read addr.
// EPI: 0 = f32 store, 1 = f32 gelu store,
//      4 = split bf16 (hi+lo) store, 5 = split bf16 transposed store (V^T)
// ---------------------------------------------------------------------------
template<int EPI, bool BIAS, int NP>
__global__ __launch_bounds__(256, 2) void gemm3_nt(
    const bf16* __restrict__ Ah, const bf16* __restrict__ Al,
    const bf16* __restrict__ Bh, const bf16* __restrict__ Bl,
    const float* __restrict__ bias, void* __restrict__ Cg, void* __restrict__ Cl,
    const int K, const int ldc, const long sA, const long sB, const long sC)
{
    constexpr int TILE = 128 * 64;                 // elems per plane per buffer
    constexpr int LOSZ = (NP == 3) ? 2 * TILE : 8; // lo planes only for NP=3
    __shared__ __align__(16) bf16 smAh[2 * TILE];
    __shared__ __align__(16) bf16 smBh[2 * TILE];
    __shared__ __align__(16) bf16 smAl[LOSZ];
    __shared__ __align__(16) bf16 smBl[LOSZ];

    const int tid  = threadIdx.x;
    const int lane = tid & 63;
    const int wave = tid >> 6;
    const int wr   = (wave >> 1) << 6;
    const int wc   = (wave & 1) << 6;
    const int l15  = lane & 15;
    const int q4   = lane >> 4;

    const long aoff = (long)blockIdx.z * sA + (long)blockIdx.x * 128 * K;
    const long boff = (long)blockIdx.z * sB + (long)blockIdx.y * 128 * K;
    const bf16* pAh = Ah + aoff;
    const bf16* pAl = (NP == 3) ? Al + aoff : nullptr;
    const bf16* pBh = Bh + boff;
    const bf16* pBl = (NP == 3) ? Bl + boff : nullptr;

    // staging: chunk = it*256 + tid; row m = chunk>>3;
    // global chunk col = (chunk&7) ^ (m&7)  (pre-swizzled source)
    int srow[4], scol[4];
#pragma unroll
    for (int it = 0; it < 4; ++it) {
        int chunk = it * 256 + tid;
        int m = chunk >> 3;
        srow[it] = m;
        scol[it] = ((chunk & 7) ^ (m & 7)) * 8;
    }

    // issue one tile's staging loads into buffer `buf` (16 gll for NP=3, 8 for NP=1)
    auto STAGE = [&](int buf, int k0) {
#pragma unroll
        for (int it = 0; it < 4; ++it) {
            const long go = (long)srow[it] * K + (k0 + scol[it]);
            const size_t lo = buf * TILE + (size_t)(it * 256 + (wave << 6)) * 8;
            GLL(pAh + go, smAh + lo);
            if constexpr (NP == 3) GLL(pAl + go, smAl + lo);
            GLL(pBh + go, smBh + lo);
            if constexpr (NP == 3) GLL(pBl + go, smBl + lo);
        }
    };

    f32x4 acc[4][4] = {};
    const int nt = K >> 6;

    STAGE(0, 0);
    for (int t = 0; t < nt; ++t) {
        const int cur = t & 1;
        if (t + 1 < nt) {
            STAGE(cur ^ 1, (t + 1) << 6);
            // wait only for the PREVIOUS tile's loads; next tile's stay in flight
            if constexpr (NP == 3) asm volatile("s_waitcnt vmcnt(16)" ::: "memory");
            else                   asm volatile("s_waitcnt vmcnt(8)"  ::: "memory");
        } else {
            asm volatile("s_waitcnt vmcnt(0)" ::: "memory");
        }
        __builtin_amdgcn_sched_barrier(0);
        __builtin_amdgcn_s_barrier();
        __builtin_amdgcn_sched_barrier(0);

        const bf16* bAh = smAh + cur * TILE;
        const bf16* bBh = smBh + cur * TILE;
        const bf16* bAl = smAl + (NP == 3 ? cur * TILE : 0);
        const bf16* bBl = smBl + (NP == 3 ? cur * TILE : 0);

#pragma unroll
        for (int kk = 0; kk < 2; ++kk) {
            bf16x8 avh[4], avl[4], bvh[4], bvl[4];
#pragma unroll
            for (int i = 0; i < 4; ++i) {
                const int rowa = wr + i * 16 + l15;
                const int ca = ((kk * 4 + q4) ^ (rowa & 7)) * 8;   // swizzled read
                avh[i] = *(const bf16x8*)(bAh + rowa * 64 + ca);
                if constexpr (NP == 3) avl[i] = *(const bf16x8*)(bAl + rowa * 64 + ca);
                const int rowb = wc + i * 16 + l15;
                const int cb = ((kk * 4 + q4) ^ (rowb & 7)) * 8;
                bvh[i] = *(const bf16x8*)(bBh + rowb * 64 + cb);
                if constexpr (NP == 3) bvl[i] = *(const bf16x8*)(bBl + rowb * 64 + cb);
            }
#pragma unroll
            for (int i = 0; i < 4; ++i)
#pragma unroll
                for (int j = 0; j < 4; ++j) {
                    acc[i][j] = __builtin_amdgcn_mfma_f32_16x16x32_bf16(
                        avh[i], bvh[j], acc[i][j], 0, 0, 0);
                    if constexpr (NP == 3) {
                        acc[i][j] = __builtin_amdgcn_mfma_f32_16x16x32_bf16(
                            avl[i], bvh[j], acc[i][j], 0, 0, 0);
                        acc[i][j] = __builtin_amdgcn_mfma_f32_16x16x32_bf16(
                            avh[i], bvl[j], acc[i][j], 0, 0, 0);
                    }
                }
        }
        __builtin_amdgcn_sched_barrier(0);
        __builtin_amdgcn_s_barrier();   // reads of buf `cur` done before next overwrite
    }

    // epilogue: D col = lane&15, row = (lane>>4)*4 + e
    const long zC = (long)blockIdx.z * sC;
    const int gcol0 = blockIdx.y * 128 + wc + l15;
    const int grow0 = blockIdx.x * 128 + wr + q4 * 4;
#pragma unroll
    for (int j = 0; j < 4; ++j) {
        const int col = gcol0 + j * 16;
        const float bvz = BIAS ? bias[col] : 0.0f;
#pragma unroll
        for (int i = 0; i < 4; ++i) {
            const int row = grow0 + i * 16;
            if (EPI == 5) {
                bf16x4 oh, ol;
#pragma unroll
                for (int e = 0; e < 4; ++e) {
                    const float v = acc[i][j][e] + bvz;
                    const bf16 hi = (bf16)v;
                    oh[e] = hi;
                    ol[e] = (bf16)(v - (float)hi);
                }
                *(bf16x4*)((bf16*)Cg + zC + (long)col * ldc + row) = oh;
                *(bf16x4*)((bf16*)Cl + zC + (long)col * ldc + row) = ol;
            } else {
#pragma unroll
                for (int e = 0; e < 4; ++e) {
                    float v = acc[i][j][e] + bvz;
                    if (EPI == 1) v = geluf(v);
                    const long off = zC + (long)(row + e) * ldc + col;
                    if (EPI == 4) {
                        const bf16 hi = (bf16)v;
                        ((bf16*)Cg)[off] = hi;
                        ((bf16*)Cl)[off] = (bf16)(v - (float)hi);
                    } else {
                        ((float*)Cg)[off] = v;
                    }
                }
            }
        }
    }
}

// ---------------------------------------------------------------------------
// y = emb[x] (f32) + sinusoidal pos -> split bf16 (hi, lo) residual
// ---------------------------------------------------------------------------
__global__ __launch_bounds__(256) void embed_k(
    const int* __restrict__ x, const float* __restrict__ emb,
    bf16* __restrict__ yh, bf16* __restrict__ yl)
{
    const int bs = blockIdx.x;          // B*S
    const int s = bs & (SEQ - 1);
    const long e0 = (long)x[bs] * DM;
    const int d = threadIdx.x * 4;
    const float4 ev = *(const float4*)(emb + e0 + d);
    float o[4];
    const float fs = (float)s;
#pragma unroll
    for (int e = 0; e < 4; ++e) {
        const int dd = d + e;
        const float div = powf(10000.0f, (float)dd * (1.0f / 1024.0f));
        const float ang = fs / div;
        const float p = (dd & 1) ? cosf(ang) : sinf(ang);
        o[e] = ((const float*)&ev)[e] + p;
    }
    bf16x4 oh, ol;
#pragma unroll
    for (int e = 0; e < 4; ++e) {
        oh[e] = (bf16)o[e];
        ol[e] = (bf16)(o[e] - (float)oh[e]);
    }
    *(bf16x4*)(yh + (long)bs * DM + d) = oh;
    *(bf16x4*)(yl + (long)bs * DM + d) = ol;
}

// ---------------------------------------------------------------------------
// f32 -> split bf16 transpose: src R x C (f32) -> dst C x R (hi, lo)
// ---------------------------------------------------------------------------
__global__ __launch_bounds__(256) void transpose_k(
    const float* __restrict__ src, bf16* __restrict__ dsth, bf16* __restrict__ dstl,
    int R, int C)
{
    __shared__ bf16 th[64][65];
    __shared__ bf16 tl[64][65];
    const int c0 = blockIdx.x * 64, r0 = blockIdx.y * 64;
    const int t = threadIdx.x;
    const int tr = t >> 4;
    const int tc = (t & 15) * 4;
#pragma unroll
    for (int p = 0; p < 4; ++p) {
        const int r = tr + p * 16;
        const float4 v = *(const float4*)(src + (long)(r0 + r) * C + c0 + tc);
        const float vv[4] = {v.x, v.y, v.z, v.w};
#pragma unroll
        for (int e = 0; e < 4; ++e) {
            const bf16 hi = (bf16)vv[e];
            th[r][tc + e] = hi;
            tl[r][tc + e] = (bf16)(vv[e] - (float)hi);
        }
    }
    __syncthreads();
#pragma unroll
    for (int p = 0; p < 4; ++p) {
        const int c = tr + p * 16;
        bf16x4 oh, ol;
#pragma unroll
        for (int e = 0; e < 4; ++e) { oh[e] = th[tc + e][c]; ol[e] = tl[tc + e][c]; }
        *(bf16x4*)(dsth + (long)(c0 + c) * R + r0 + tc) = oh;
        *(bf16x4*)(dstl + (long)(c0 + c) * R + r0 + tc) = ol;
    }
}

// ---------------------------------------------------------------------------
// Row softmax: 2048 f32 per row -> split bf16 (hi, lo)
// ---------------------------------------------------------------------------
__global__ __launch_bounds__(256) void softmax_k(
    const float* __restrict__ S, bf16* __restrict__ Ph, bf16* __restrict__ Pl)
{
    const long row = blockIdx.x;
    const float4* src = (const float4*)(S + (row << 11));
    const int t = threadIdx.x;
    float4 a = src[t], b = src[256 + t];
    float m = fmaxf(fmaxf(fmaxf(a.x, a.y), fmaxf(a.z, a.w)),
                    fmaxf(fmaxf(b.x, b.y), fmaxf(b.z, b.w)));
#pragma unroll
    for (int o = 32; o; o >>= 1) m = fmaxf(m, __shfl_xor(m, o));
    __shared__ float red1[4], red2[4];
    const int wv = t >> 6;
    if ((t & 63) == 0) red1[wv] = m;
    __syncthreads();
    m = fmaxf(fmaxf(red1[0], red1[1]), fmaxf(red1[2], red1[3]));

    a.x = expf(a.x - m); a.y = expf(a.y - m); a.z = expf(a.z - m); a.w = expf(a.w - m);
    b.x = expf(b.x - m); b.y = expf(b.y - m); b.z = expf(b.z - m); b.w = expf(b.w - m);
    float s = a.x + a.y + a.z + a.w + b.x + b.y + b.z + b.w;
#pragma unroll
    for (int o = 32; o; o >>= 1) s += __shfl_xor(s, o);
    if ((t & 63) == 0) red2[wv] = s;
    __syncthreads();
    s = red2[0] + red2[1] + red2[2] + red2[3];
    const float inv = 1.0f / s;

    const float pv[8] = {a.x * inv, a.y * inv, a.z * inv, a.w * inv,
                         b.x * inv, b.y * inv, b.z * inv, b.w * inv};
    bf16x4 h0, l0, h1, l1;
#pragma unroll
    for (int e = 0; e < 4; ++e) {
        const bf16 hi = (bf16)pv[e];
        h0[e] = hi; l0[e] = (bf16)(pv[e] - (float)hi);
        const bf16 hj = (bf16)pv[4 + e];
        h1[e] = hj; l1[e] = (bf16)(pv[4 + e] - (float)hj);
    }
    *(bf16x4*)(Ph + (row << 11) + t * 4) = h0;
    *(bf16x4*)(Pl + (row << 11) + t * 4) = l0;
    *(bf16x4*)(Ph + (row << 11) + 1024 + t * 4) = h1;
    *(bf16x4*)(Pl + (row << 11) + 1024 + t * 4) = l1;
}

// ---------------------------------------------------------------------------
// LayerNorm over whole (S,D) sample; residual carried as split bf16 (hi+lo).
// ---------------------------------------------------------------------------
__global__ __launch_bounds__(256) void ln_stats_k(
    const bf16* __restrict__ yh, const bf16* __restrict__ yl,
    const float* __restrict__ r, float2* __restrict__ part)
{
    const int b = blockIdx.y;
    const long base = (long)b * SD + (long)blockIdx.x * (SD / 64);
    float s = 0.f, q = 0.f;
    for (int i = threadIdx.x; i < (SD / 64) / 4; i += 256) {
        const bf16x4 h = *(const bf16x4*)(yh + base + i * 4);
        const bf16x4 l = *(const bf16x4*)(yl + base + i * 4);
        const float4 c = *(const float4*)(r + base + i * 4);
        const float cc[4] = {c.x, c.y, c.z, c.w};
#pragma unroll
        for (int e = 0; e < 4; ++e) {
            const float x = (float)h[e] + (float)l[e] + cc[e];
            s += x; q += x * x;
        }
    }
#pragma unroll
    for (int o = 32; o; o >>= 1) { s += __shfl_xor(s, o); q += __shfl_xor(q, o); }
    __shared__ float rs[4], rq[4];
    const int wv = threadIdx.x >> 6;
    if ((threadIdx.x & 63) == 0) { rs[wv] = s; rq[wv] = q; }
    __syncthreads();
    if (threadIdx.x == 0)
        part[b * 64 + blockIdx.x] = make_float2(rs[0] + rs[1] + rs[2] + rs[3],
                                                rq[0] + rq[1] + rq[2] + rq[3]);
}

__global__ void ln_fin_k(const float2* __restrict__ part, float2* __restrict__ stats)
{
    const int b = blockIdx.x;
    const float2 p = part[b * 64 + threadIdx.x];
    float s = p.x, q = p.y;
#pragma unroll
    for (int o = 32; o; o >>= 1) { s += __shfl_xor(s, o); q += __shfl_xor(q, o); }
    if (threadIdx.x == 0) {
        const float inv_n = 1.0f / (float)SD;
        const float mean = s * inv_n;
        const float var = fmaxf(q * inv_n - mean * mean, 0.f);
        stats[b] = make_float2(mean, rsqrtf(var + 1e-5f));
    }
}

__global__ __launch_bounds__(256) void ln_apply_k(
    const bf16* __restrict__ yh_in, const bf16* __restrict__ yl_in,
    const float* __restrict__ r,
    const float* __restrict__ w, const float* __restrict__ bb,
    const float2* __restrict__ stats,
    bf16* __restrict__ yh_out, bf16* __restrict__ yl_out, float* __restrict__ fout)
{
    const long i = ((long)blockIdx.x * 256 + threadIdx.x) * 4;
    const int smp = (int)(i >> 21);
    const long sd = i & (SD - 1);
    const float2 st = stats[smp];
    const bf16x4 h = *(const bf16x4*)(yh_in + i);
    const bf16x4 l = *(const bf16x4*)(yl_in + i);
    const float4 c = *(const float4*)(r + i);
    const float4 wv = *(const float4*)(w + sd);
    const float4 bv = *(const float4*)(bb + sd);
    const float cc[4] = {c.x, c.y, c.z, c.w};
    const float ww[4] = {wv.x, wv.y, wv.z, wv.w};
    const float bbx[4] = {bv.x, bv.y, bv.z, bv.w};
    float o[4];
#pragma unroll
    for (int e = 0; e < 4; ++e) {
        const float x = (float)h[e] + (float)l[e] + cc[e];
        o[e] = (x - st.x) * st.y * ww[e] + bbx[e];
    }
    bf16x4 oh, ol;
#pragma unroll
    for (int e = 0; e < 4; ++e) {
        oh[e] = (bf16)o[e];
        ol[e] = (bf16)(o[e] - (float)oh[e]);
    }
    *(bf16x4*)(yh_out + i) = oh;
    *(bf16x4*)(yl_out + i) = ol;
    if (fout != nullptr) *(float4*)(fout + i) = *(float4*)o;
}

// ---------------------------------------------------------------------------
extern "C" void kernel_launch(void* const* d_in, const int* in_sizes, int n_in,
                              void* d_out, int out_size, void* d_ws, size_t ws_size,
                              hipStream_t stream)
{
    (void)in_sizes; (void)n_in; (void)out_size; (void)ws_size;

    const int*   x    = (const int*)  d_in[0];
    const float* emb  = (const float*)d_in[1];
    const float* wq   = (const float*)d_in[2];
    const float* bq   = (const float*)d_in[3];
    const float* wk   = (const float*)d_in[4];
    const float* bk   = (const float*)d_in[5];
    const float* wv   = (const float*)d_in[6];
    const float* bv   = (const float*)d_in[7];
    const float* wo   = (const float*)d_in[8];
    const float* bo   = (const float*)d_in[9];
    const float* w1   = (const float*)d_in[10];
    const float* b1   = (const float*)d_in[11];
    const float* w2   = (const float*)d_in[12];
    const float* b2   = (const float*)d_in[13];
    const float* ln1w = (const float*)d_in[14];
    const float* ln1b = (const float*)d_in[15];
    const float* ln2w = (const float*)d_in[16];
    const float* ln2b = (const float*)d_in[17];

    // Workspace — peak 368 MiB + 16 KiB (proven-safe band).
    char* ws = (char*)d_ws;
    const size_t MB = (size_t)1 << 20;
    bf16*   ybh   = (bf16*) (ws);                  //  16 MiB residual hi
    bf16*   ybl   = (bf16*) (ws + 16  * MB);       //  16 MiB residual lo
    bf16*   wT    = (bf16*) (ws + 32  * MB);       //  48 MiB: 6 x 8 MiB weight slots
    bf16*   atth  = (bf16*) (ws + 80  * MB);       //  64 MiB att hi [8192][4096]
    bf16*   attl  = (bf16*) (ws + 144 * MB);       //  64 MiB att lo
    // per-half (2-batch) attention scratch, 208..368:
    bf16*   qh    = (bf16*) (ws + 208 * MB);       //  32 MiB [2][2048][4096]
    bf16*   ql    = (bf16*) (ws + 240 * MB);       //  32 MiB
    bf16*   kh    = (bf16*) (ws + 272 * MB);       //  32 MiB
    bf16*   kl    = (bf16*) (ws + 304 * MB);       //  32 MiB
    float*  scf   = (float*)(ws + 336 * MB);       //  32 MiB f32 [2][2048][2048]
    bf16*   pbh   = (bf16*) (ws + 208 * MB);       //  16 MiB probs hi  (q dead)
    bf16*   pbl   = (bf16*) (ws + 224 * MB);       //  16 MiB probs lo
    bf16*   vTh   = (bf16*) (ws + 272 * MB);       //  32 MiB V^T hi    (k dead)
    bf16*   vTl   = (bf16*) (ws + 304 * MB);       //  32 MiB V^T lo
    // post-attention f32 outputs (per-half region dead):
    float*  attout= (float*)(ws + 208 * MB);       //  32 MiB f32 [8192][1024]
    float*  ffnf  = (float*)(ws + 208 * MB);       //  32 MiB f32
    bf16*   hh    = atth;                          //  64 MiB h hi (att dead after O-proj)
    bf16*   hl    = attl;                          //  64 MiB h lo
    float2* part  = (float2*)(ws + 368 * MB);      //  LN partials
    float2* stats = (float2*)(ws + 368 * MB + 8192);

    const long TSZ = (long)DM * HD;
    bf16* slot[6];
    for (int s = 0; s < 6; ++s) slot[s] = wT + (long)s * TSZ;

    embed_k<<<NB * SEQ, 256, 0, stream>>>(x, emb, ybh, ybl);

    for (int l = 0; l < 2; ++l) {
        // ---- phase 1 weights: wq, wk, wv (split, K-contiguous) ----
        bf16 *wqH = slot[0], *wqL = slot[1], *wkH = slot[2], *wkL = slot[3],
             *wvH = slot[4], *wvL = slot[5];
        transpose_k<<<dim3(64, 16), 256, 0, stream>>>(wq + l * TSZ, wqH, wqL, DM, HD);
        transpose_k<<<dim3(64, 16), 256, 0, stream>>>(wk + l * TSZ, wkH, wkL, DM, HD);
        transpose_k<<<dim3(64, 16), 256, 0, stream>>>(wv + l * TSZ, wvH, wvL, DM, HD);

        // ---- attention in two 2-batch halves (z = batch within half) ----
        for (int h2 = 0; h2 < 2; ++h2) {
            const long yofs = (long)(2 * h2) * SD;
            // q = y@wq + bq  (score-critical: always NP=3)
            gemm3_nt<4, true, 3><<<dim3(16, 32, 2), 256, 0, stream>>>(
                ybh + yofs, ybl + yofs, wqH, wqL, bq + l * HD, qh, ql,
                DM, HD, SD, 0, (long)SEQ * HD);
            // k = y@wk + bk
            gemm3_nt<4, true, 3><<<dim3(16, 32, 2), 256, 0, stream>>>(
                ybh + yofs, ybl + yofs, wkH, wkL, bk + l * HD, kh, kl,
                DM, HD, SD, 0, (long)SEQ * HD);
            // scores = q@k^T -> f32 (score-critical: always NP=3)
            gemm3_nt<0, false, 3><<<dim3(16, 16, 2), 256, 0, stream>>>(
                qh, ql, kh, kl, nullptr, scf, nullptr,
                HD, SEQ, (long)SEQ * HD, (long)SEQ * HD, (long)SEQ * SEQ);
            // softmax -> split probs (into dead q region)
            softmax_k<<<2 * SEQ, 256, 0, stream>>>(scf, pbh, pbl);
            // v = y@wv + bv, split transposed -> vT (layer 2: post-score, NP=1)
            if (l == 0)
                gemm3_nt<5, true, 3><<<dim3(16, 32, 2), 256, 0, stream>>>(
                    ybh + yofs, ybl + yofs, wvH, wvL, bv + l * HD, vTh, vTl,
                    DM, SEQ, SD, 0, (long)HD * SEQ);
            else
                gemm3_nt<5, true, 1><<<dim3(16, 32, 2), 256, 0, stream>>>(
                    ybh + yofs, nullptr, wvH, nullptr, bv + l * HD, vTh, vTl,
                    DM, SEQ, SD, 0, (long)HD * SEQ);
            // att = P@V -> split bf16 (layer 2: NP=1)
            if (l == 0)
                gemm3_nt<4, false, 3><<<dim3(16, 32, 2), 256, 0, stream>>>(
                    pbh, pbl, vTh, vTl, nullptr,
                    atth + yofs * 4, attl + yofs * 4,
                    SEQ, HD, (long)SEQ * SEQ, (long)HD * SEQ, (long)SEQ * HD);
            else
                gemm3_nt<4, false, 1><<<dim3(16, 32, 2), 256, 0, stream>>>(
                    pbh, nullptr, vTh, nullptr, nullptr,
                    atth + yofs * 4, attl + yofs * 4,
                    SEQ, HD, (long)SEQ * SEQ, (long)HD * SEQ, (long)SEQ * HD);
        }

        // ---- phase 2 weights: wo, w1, w2 (wq/wk/wv dead) ----
        bf16 *woH = slot[0], *woL = slot[1], *w1H = slot[2], *w1L = slot[3],
             *w2H = slot[4], *w2L = slot[5];
        transpose_k<<<dim3(16, 64), 256, 0, stream>>>(wo + l * TSZ, woH, woL, HD, DM);
        transpose_k<<<dim3(64, 16), 256, 0, stream>>>(w1 + l * TSZ, w1H, w1L, DM, HD);
        transpose_k<<<dim3(16, 64), 256, 0, stream>>>(w2 + l * TSZ, w2H, w2L, HD, DM);

        // attout = att@wo + bo -> f32 (layer 2: NP=1)
        if (l == 0)
            gemm3_nt<0, true, 3><<<dim3(64, 8, 1), 256, 0, stream>>>(
                atth, attl, woH, woL, bo + l * DM, attout, nullptr, HD, DM, 0, 0, 0);
        else
            gemm3_nt<0, true, 1><<<dim3(64, 8, 1), 256, 0, stream>>>(
                atth, nullptr, woH, nullptr, bo + l * DM, attout, nullptr, HD, DM, 0, 0, 0);
        // LN1(y + attout)
        ln_stats_k<<<dim3(64, NB), 256, 0, stream>>>(ybh, ybl, attout, part);
        ln_fin_k  <<<NB, 64, 0, stream>>>(part, stats);
        ln_apply_k<<<8192, 256, 0, stream>>>(ybh, ybl, attout,
                                             ln1w + (long)l * SD, ln1b + (long)l * SD,
                                             stats, ybh, ybl, nullptr);
        // h = y@w1 + b1 -> split bf16 (layer 2: NP=1)
        if (l == 0)
            gemm3_nt<4, true, 3><<<dim3(64, 32, 1), 256, 0, stream>>>(
                ybh, ybl, w1H, w1L, b1 + l * HD, hh, hl, DM, HD, 0, 0, 0);
        else
            gemm3_nt<4, true, 1><<<dim3(64, 32, 1), 256, 0, stream>>>(
                ybh, nullptr, w1H, nullptr, b1 + l * HD, hh, hl, DM, HD, 0, 0, 0);
        // ffn = gelu(h@w2 + b2) -> f32 (layer 2: NP=1)
        if (l == 0)
            gemm3_nt<1, true, 3><<<dim3(64, 8, 1), 256, 0, stream>>>(
                hh, hl, w2H, w2L, b2 + l * DM, ffnf, nullptr, HD, DM, 0, 0, 0);
        else
            gemm3_nt<1, true, 1><<<dim3(64, 8, 1), 256, 0, stream>>>(
                hh, nullptr, w2H, nullptr, b2 + l * DM, ffnf, nullptr, HD, DM, 0, 0, 0);
        // LN2(y + ffn); final layer also writes f32 to d_out
        float* fdst = (l == 1) ? (float*)d_out : nullptr;
        ln_stats_k<<<dim3(64, NB), 256, 0, stream>>>(ybh, ybl, ffnf, part);
        ln_fin_k  <<<NB, 64, 0, stream>>>(part, stats);
        ln_apply_k<<<8192, 256, 0, stream>>>(ybh, ybl, ffnf,
                                             ln2w + (long)l * SD, ln2b + (long)l * SD,
                                             stats, ybh, ybl, fdst);
    }
}

// Round 10
// 3422.986 us; speedup vs baseline: 1.3940x; 1.3940x over previous
//
#include <hip/hip_runtime.h>
#include <cstdint>
#include <cstddef>

using bf16 = __bf16;
typedef float f32x4 __attribute__((ext_vector_type(4)));
typedef bf16 bf16x8 __attribute__((ext_vector_type(8)));
typedef bf16 bf16x4 __attribute__((ext_vector_type(4)));

#define NB 4           // batch
#define SEQ 2048
#define DM 1024        // d_model
#define HD 4096        // hidden
#define SD (SEQ*DM)    // 2^21 elems per sample

__device__ __forceinline__ float geluf(float v) {
    return 0.5f * v * (1.0f + erff(v * 0.70710678118654752f));
}

#define GLL(gp, lp) __builtin_amdgcn_global_load_lds( \
    (const __attribute__((address_space(1))) void*)(gp), \
    (__attribute__((address_space(3))) void*)(lp), 16, 0, 0)

// ---------------------------------------------------------------------------
// Split-precision NT GEMM, fused NP-pass, single-buffered (R8 structure —
// 2 blocks/CU implicit overlap; R9's 128KB dbuf pipeline REGRESSED to
// 1 wave/SIMD and is reverted):
//   NP=3: C = Ah*Bh + Al*Bh + Ah*Bl  (~17-bit mantissa, f32 accum)
//   NP=1: C = Ah*Bh                  (plain bf16; 32KB LDS -> 4 blocks/CU)
// A: M x K row-major bf16 (pair), Bt: N x K row-major bf16 (pair).
// Tile 128x128x64, 4 waves, 16x16x32 bf16 MFMA, global_load_lds staging,
// chunk XOR swizzle (c' = c ^ (m&7)) on BOTH global source and ds_read addr.
// EPI: 0 = f32 store, 1 = f32 gelu store,
//      4 = split bf16 (hi+lo) store, 5 = split bf16 transposed store (V^T)
// ---------------------------------------------------------------------------
template<int EPI, bool BIAS, int NP>
__global__ __launch_bounds__(256, NP == 1 ? 4 : 2) void gemm3_nt(
    const bf16* __restrict__ Ah, const bf16* __restrict__ Al,
    const bf16* __restrict__ Bh, const bf16* __restrict__ Bl,
    const float* __restrict__ bias, void* __restrict__ Cg, void* __restrict__ Cl,
    const int K, const int ldc, const long sA, const long sB, const long sC)
{
    constexpr int TILE = 128 * 64;                 // elems per plane
    constexpr int LOSZ = (NP == 3) ? TILE : 8;     // lo planes only for NP=3
    __shared__ __align__(16) bf16 smAh[TILE];
    __shared__ __align__(16) bf16 smBh[TILE];
    __shared__ __align__(16) bf16 smAl[LOSZ];
    __shared__ __align__(16) bf16 smBl[LOSZ];

    const int tid  = threadIdx.x;
    const int lane = tid & 63;
    const int wave = tid >> 6;
    const int wr   = (wave >> 1) << 6;
    const int wc   = (wave & 1) << 6;
    const int l15  = lane & 15;
    const int q4   = lane >> 4;

    const long aoff = (long)blockIdx.z * sA + (long)blockIdx.x * 128 * K;
    const long boff = (long)blockIdx.z * sB + (long)blockIdx.y * 128 * K;
    const bf16* pAh = Ah + aoff;
    const bf16* pAl = (NP == 3) ? Al + aoff : nullptr;
    const bf16* pBh = Bh + boff;
    const bf16* pBl = (NP == 3) ? Bl + boff : nullptr;

    // staging: chunk = it*256 + tid; row m = chunk>>3;
    // global chunk col = (chunk&7) ^ (m&7)  (pre-swizzled source)
    int srow[4], scol[4];
#pragma unroll
    for (int it = 0; it < 4; ++it) {
        int chunk = it * 256 + tid;
        int m = chunk >> 3;
        srow[it] = m;
        scol[it] = ((chunk & 7) ^ (m & 7)) * 8;
    }

    f32x4 acc[4][4] = {};

    for (int k0 = 0; k0 < K; k0 += 64) {
#pragma unroll
        for (int it = 0; it < 4; ++it) {
            const long go = (long)srow[it] * K + (k0 + scol[it]);
            const size_t lo = (size_t)(it * 256 + (wave << 6)) * 8;   // linear fill
            GLL(pAh + go, smAh + lo);
            if constexpr (NP == 3) GLL(pAl + go, smAl + lo);
            GLL(pBh + go, smBh + lo);
            if constexpr (NP == 3) GLL(pBl + go, smBl + lo);
        }
        __syncthreads();   // compiler drains vmcnt(0) before barrier

#pragma unroll
        for (int kk = 0; kk < 2; ++kk) {
            bf16x8 avh[4], avl[4], bvh[4], bvl[4];
#pragma unroll
            for (int i = 0; i < 4; ++i) {
                const int rowa = wr + i * 16 + l15;
                const int ca = ((kk * 4 + q4) ^ (rowa & 7)) * 8;   // swizzled read
                avh[i] = *(const bf16x8*)(smAh + rowa * 64 + ca);
                if constexpr (NP == 3) avl[i] = *(const bf16x8*)(smAl + rowa * 64 + ca);
                const int rowb = wc + i * 16 + l15;
                const int cb = ((kk * 4 + q4) ^ (rowb & 7)) * 8;
                bvh[i] = *(const bf16x8*)(smBh + rowb * 64 + cb);
                if constexpr (NP == 3) bvl[i] = *(const bf16x8*)(smBl + rowb * 64 + cb);
            }
#pragma unroll
            for (int i = 0; i < 4; ++i)
#pragma unroll
                for (int j = 0; j < 4; ++j) {
                    acc[i][j] = __builtin_amdgcn_mfma_f32_16x16x32_bf16(
                        avh[i], bvh[j], acc[i][j], 0, 0, 0);
                    if constexpr (NP == 3) {
                        acc[i][j] = __builtin_amdgcn_mfma_f32_16x16x32_bf16(
                            avl[i], bvh[j], acc[i][j], 0, 0, 0);
                        acc[i][j] = __builtin_amdgcn_mfma_f32_16x16x32_bf16(
                            avh[i], bvl[j], acc[i][j], 0, 0, 0);
                    }
                }
        }
        __syncthreads();
    }

    // epilogue: D col = lane&15, row = (lane>>4)*4 + e
    const long zC = (long)blockIdx.z * sC;
    const int gcol0 = blockIdx.y * 128 + wc + l15;
    const int grow0 = blockIdx.x * 128 + wr + q4 * 4;
#pragma unroll
    for (int j = 0; j < 4; ++j) {
        const int col = gcol0 + j * 16;
        const float bvz = BIAS ? bias[col] : 0.0f;
#pragma unroll
        for (int i = 0; i < 4; ++i) {
            const int row = grow0 + i * 16;
            if (EPI == 5) {
                bf16x4 oh, ol;
#pragma unroll
                for (int e = 0; e < 4; ++e) {
                    const float v = acc[i][j][e] + bvz;
                    const bf16 hi = (bf16)v;
                    oh[e] = hi;
                    ol[e] = (bf16)(v - (float)hi);
                }
                *(bf16x4*)((bf16*)Cg + zC + (long)col * ldc + row) = oh;
                *(bf16x4*)((bf16*)Cl + zC + (long)col * ldc + row) = ol;
            } else {
#pragma unroll
                for (int e = 0; e < 4; ++e) {
                    float v = acc[i][j][e] + bvz;
                    if (EPI == 1) v = geluf(v);
                    const long off = zC + (long)(row + e) * ldc + col;
                    if (EPI == 4) {
                        const bf16 hi = (bf16)v;
                        ((bf16*)Cg)[off] = hi;
                        ((bf16*)Cl)[off] = (bf16)(v - (float)hi);
                    } else {
                        ((float*)Cg)[off] = v;
                    }
                }
            }
        }
    }
}

// ---------------------------------------------------------------------------
// y = emb[x] (f32) + sinusoidal pos -> split bf16 (hi, lo) residual
// ---------------------------------------------------------------------------
__global__ __launch_bounds__(256) void embed_k(
    const int* __restrict__ x, const float* __restrict__ emb,
    bf16* __restrict__ yh, bf16* __restrict__ yl)
{
    const int bs = blockIdx.x;          // B*S
    const int s = bs & (SEQ - 1);
    const long e0 = (long)x[bs] * DM;
    const int d = threadIdx.x * 4;
    const float4 ev = *(const float4*)(emb + e0 + d);
    float o[4];
    const float fs = (float)s;
#pragma unroll
    for (int e = 0; e < 4; ++e) {
        const int dd = d + e;
        const float div = powf(10000.0f, (float)dd * (1.0f / 1024.0f));
        const float ang = fs / div;
        const float p = (dd & 1) ? cosf(ang) : sinf(ang);
        o[e] = ((const float*)&ev)[e] + p;
    }
    bf16x4 oh, ol;
#pragma unroll
    for (int e = 0; e < 4; ++e) {
        oh[e] = (bf16)o[e];
        ol[e] = (bf16)(o[e] - (float)oh[e]);
    }
    *(bf16x4*)(yh + (long)bs * DM + d) = oh;
    *(bf16x4*)(yl + (long)bs * DM + d) = ol;
}

// ---------------------------------------------------------------------------
// f32 -> split bf16 transpose: src R x C (f32) -> dst C x R (hi, lo)
// ---------------------------------------------------------------------------
__global__ __launch_bounds__(256) void transpose_k(
    const float* __restrict__ src, bf16* __restrict__ dsth, bf16* __restrict__ dstl,
    int R, int C)
{
    __shared__ bf16 th[64][65];
    __shared__ bf16 tl[64][65];
    const int c0 = blockIdx.x * 64, r0 = blockIdx.y * 64;
    const int t = threadIdx.x;
    const int tr = t >> 4;
    const int tc = (t & 15) * 4;
#pragma unroll
    for (int p = 0; p < 4; ++p) {
        const int r = tr + p * 16;
        const float4 v = *(const float4*)(src + (long)(r0 + r) * C + c0 + tc);
        const float vv[4] = {v.x, v.y, v.z, v.w};
#pragma unroll
        for (int e = 0; e < 4; ++e) {
            const bf16 hi = (bf16)vv[e];
            th[r][tc + e] = hi;
            tl[r][tc + e] = (bf16)(vv[e] - (float)hi);
        }
    }
    __syncthreads();
#pragma unroll
    for (int p = 0; p < 4; ++p) {
        const int c = tr + p * 16;
        bf16x4 oh, ol;
#pragma unroll
        for (int e = 0; e < 4; ++e) { oh[e] = th[tc + e][c]; ol[e] = tl[tc + e][c]; }
        *(bf16x4*)(dsth + (long)(c0 + c) * R + r0 + tc) = oh;
        *(bf16x4*)(dstl + (long)(c0 + c) * R + r0 + tc) = ol;
    }
}

// ---------------------------------------------------------------------------
// Row softmax: 2048 f32 per row -> split bf16 (hi, lo)
// ---------------------------------------------------------------------------
__global__ __launch_bounds__(256) void softmax_k(
    const float* __restrict__ S, bf16* __restrict__ Ph, bf16* __restrict__ Pl)
{
    const long row = blockIdx.x;
    const float4* src = (const float4*)(S + (row << 11));
    const int t = threadIdx.x;
    float4 a = src[t], b = src[256 + t];
    float m = fmaxf(fmaxf(fmaxf(a.x, a.y), fmaxf(a.z, a.w)),
                    fmaxf(fmaxf(b.x, b.y), fmaxf(b.z, b.w)));
#pragma unroll
    for (int o = 32; o; o >>= 1) m = fmaxf(m, __shfl_xor(m, o));
    __shared__ float red1[4], red2[4];
    const int wv = t >> 6;
    if ((t & 63) == 0) red1[wv] = m;
    __syncthreads();
    m = fmaxf(fmaxf(red1[0], red1[1]), fmaxf(red1[2], red1[3]));

    a.x = expf(a.x - m); a.y = expf(a.y - m); a.z = expf(a.z - m); a.w = expf(a.w - m);
    b.x = expf(b.x - m); b.y = expf(b.y - m); b.z = expf(b.z - m); b.w = expf(b.w - m);
    float s = a.x + a.y + a.z + a.w + b.x + b.y + b.z + b.w;
#pragma unroll
    for (int o = 32; o; o >>= 1) s += __shfl_xor(s, o);
    if ((t & 63) == 0) red2[wv] = s;
    __syncthreads();
    s = red2[0] + red2[1] + red2[2] + red2[3];
    const float inv = 1.0f / s;

    const float pv[8] = {a.x * inv, a.y * inv, a.z * inv, a.w * inv,
                         b.x * inv, b.y * inv, b.z * inv, b.w * inv};
    bf16x4 h0, l0, h1, l1;
#pragma unroll
    for (int e = 0; e < 4; ++e) {
        const bf16 hi = (bf16)pv[e];
        h0[e] = hi; l0[e] = (bf16)(pv[e] - (float)hi);
        const bf16 hj = (bf16)pv[4 + e];
        h1[e] = hj; l1[e] = (bf16)(pv[4 + e] - (float)hj);
    }
    *(bf16x4*)(Ph + (row << 11) + t * 4) = h0;
    *(bf16x4*)(Pl + (row << 11) + t * 4) = l0;
    *(bf16x4*)(Ph + (row << 11) + 1024 + t * 4) = h1;
    *(bf16x4*)(Pl + (row << 11) + 1024 + t * 4) = l1;
}

// ---------------------------------------------------------------------------
// LayerNorm over whole (S,D) sample; residual carried as split bf16 (hi+lo).
// ---------------------------------------------------------------------------
__global__ __launch_bounds__(256) void ln_stats_k(
    const bf16* __restrict__ yh, const bf16* __restrict__ yl,
    const float* __restrict__ r, float2* __restrict__ part)
{
    const int b = blockIdx.y;
    const long base = (long)b * SD + (long)blockIdx.x * (SD / 64);
    float s = 0.f, q = 0.f;
    for (int i = threadIdx.x; i < (SD / 64) / 4; i += 256) {
        const bf16x4 h = *(const bf16x4*)(yh + base + i * 4);
        const bf16x4 l = *(const bf16x4*)(yl + base + i * 4);
        const float4 c = *(const float4*)(r + base + i * 4);
        const float cc[4] = {c.x, c.y, c.z, c.w};
#pragma unroll
        for (int e = 0; e < 4; ++e) {
            const float x = (float)h[e] + (float)l[e] + cc[e];
            s += x; q += x * x;
        }
    }
#pragma unroll
    for (int o = 32; o; o >>= 1) { s += __shfl_xor(s, o); q += __shfl_xor(q, o); }
    __shared__ float rs[4], rq[4];
    const int wv = threadIdx.x >> 6;
    if ((threadIdx.x & 63) == 0) { rs[wv] = s; rq[wv] = q; }
    __syncthreads();
    if (threadIdx.x == 0)
        part[b * 64 + blockIdx.x] = make_float2(rs[0] + rs[1] + rs[2] + rs[3],
                                                rq[0] + rq[1] + rq[2] + rq[3]);
}

__global__ void ln_fin_k(const float2* __restrict__ part, float2* __restrict__ stats)
{
    const int b = blockIdx.x;
    const float2 p = part[b * 64 + threadIdx.x];
    float s = p.x, q = p.y;
#pragma unroll
    for (int o = 32; o; o >>= 1) { s += __shfl_xor(s, o); q += __shfl_xor(q, o); }
    if (threadIdx.x == 0) {
        const float inv_n = 1.0f / (float)SD;
        const float mean = s * inv_n;
        const float var = fmaxf(q * inv_n - mean * mean, 0.f);
        stats[b] = make_float2(mean, rsqrtf(var + 1e-5f));
    }
}

__global__ __launch_bounds__(256) void ln_apply_k(
    const bf16* __restrict__ yh_in, const bf16* __restrict__ yl_in,
    const float* __restrict__ r,
    const float* __restrict__ w, const float* __restrict__ bb,
    const float2* __restrict__ stats,
    bf16* __restrict__ yh_out, bf16* __restrict__ yl_out, float* __restrict__ fout)
{
    const long i = ((long)blockIdx.x * 256 + threadIdx.x) * 4;
    const int smp = (int)(i >> 21);
    const long sd = i & (SD - 1);
    const float2 st = stats[smp];
    const bf16x4 h = *(const bf16x4*)(yh_in + i);
    const bf16x4 l = *(const bf16x4*)(yl_in + i);
    const float4 c = *(const float4*)(r + i);
    const float4 wv = *(const float4*)(w + sd);
    const float4 bv = *(const float4*)(bb + sd);
    const float cc[4] = {c.x, c.y, c.z, c.w};
    const float ww[4] = {wv.x, wv.y, wv.z, wv.w};
    const float bbx[4] = {bv.x, bv.y, bv.z, bv.w};
    float o[4];
#pragma unroll
    for (int e = 0; e < 4; ++e) {
        const float x = (float)h[e] + (float)l[e] + cc[e];
        o[e] = (x - st.x) * st.y * ww[e] + bbx[e];
    }
    bf16x4 oh, ol;
#pragma unroll
    for (int e = 0; e < 4; ++e) {
        oh[e] = (bf16)o[e];
        ol[e] = (bf16)(o[e] - (float)oh[e]);
    }
    *(bf16x4*)(yh_out + i) = oh;
    *(bf16x4*)(yl_out + i) = ol;
    if (fout != nullptr) *(float4*)(fout + i) = *(float4*)o;
}

// ---------------------------------------------------------------------------
extern "C" void kernel_launch(void* const* d_in, const int* in_sizes, int n_in,
                              void* d_out, int out_size, void* d_ws, size_t ws_size,
                              hipStream_t stream)
{
    (void)in_sizes; (void)n_in; (void)out_size; (void)ws_size;

    const int*   x    = (const int*)  d_in[0];
    const float* emb  = (const float*)d_in[1];
    const float* wq   = (const float*)d_in[2];
    const float* bq   = (const float*)d_in[3];
    const float* wk   = (const float*)d_in[4];
    const float* bk   = (const float*)d_in[5];
    const float* wv   = (const float*)d_in[6];
    const float* bv   = (const float*)d_in[7];
    const float* wo   = (const float*)d_in[8];
    const float* bo   = (const float*)d_in[9];
    const float* w1   = (const float*)d_in[10];
    const float* b1   = (const float*)d_in[11];
    const float* w2   = (const float*)d_in[12];
    const float* b2   = (const float*)d_in[13];
    const float* ln1w = (const float*)d_in[14];
    const float* ln1b = (const float*)d_in[15];
    const float* ln2w = (const float*)d_in[16];
    const float* ln2b = (const float*)d_in[17];

    // Workspace — peak 368 MiB + 16 KiB (proven-safe band).
    char* ws = (char*)d_ws;
    const size_t MB = (size_t)1 << 20;
    bf16*   ybh   = (bf16*) (ws);                  //  16 MiB residual hi
    bf16*   ybl   = (bf16*) (ws + 16  * MB);       //  16 MiB residual lo
    bf16*   wT    = (bf16*) (ws + 32  * MB);       //  48 MiB: 6 x 8 MiB weight slots
    bf16*   atth  = (bf16*) (ws + 80  * MB);       //  64 MiB att hi [8192][4096]
    bf16*   attl  = (bf16*) (ws + 144 * MB);       //  64 MiB att lo
    // per-half (2-batch) attention scratch, 208..368:
    bf16*   qh    = (bf16*) (ws + 208 * MB);       //  32 MiB [2][2048][4096]
    bf16*   ql    = (bf16*) (ws + 240 * MB);       //  32 MiB
    bf16*   kh    = (bf16*) (ws + 272 * MB);       //  32 MiB
    bf16*   kl    = (bf16*) (ws + 304 * MB);       //  32 MiB
    float*  scf   = (float*)(ws + 336 * MB);       //  32 MiB f32 [2][2048][2048]
    bf16*   pbh   = (bf16*) (ws + 208 * MB);       //  16 MiB probs hi  (q dead)
    bf16*   pbl   = (bf16*) (ws + 224 * MB);       //  16 MiB probs lo
    bf16*   vTh   = (bf16*) (ws + 272 * MB);       //  32 MiB V^T hi    (k dead)
    bf16*   vTl   = (bf16*) (ws + 304 * MB);       //  32 MiB V^T lo
    // post-attention f32 outputs (per-half region dead):
    float*  attout= (float*)(ws + 208 * MB);       //  32 MiB f32 [8192][1024]
    float*  ffnf  = (float*)(ws + 208 * MB);       //  32 MiB f32
    bf16*   hh    = atth;                          //  64 MiB h hi (att dead after O-proj)
    bf16*   hl    = attl;                          //  64 MiB h lo
    float2* part  = (float2*)(ws + 368 * MB);      //  LN partials
    float2* stats = (float2*)(ws + 368 * MB + 8192);

    const long TSZ = (long)DM * HD;
    bf16* slot[6];
    for (int s = 0; s < 6; ++s) slot[s] = wT + (long)s * TSZ;

    embed_k<<<NB * SEQ, 256, 0, stream>>>(x, emb, ybh, ybl);

    for (int l = 0; l < 2; ++l) {
        // ---- phase 1 weights: wq, wk, wv (split, K-contiguous) ----
        bf16 *wqH = slot[0], *wqL = slot[1], *wkH = slot[2], *wkL = slot[3],
             *wvH = slot[4], *wvL = slot[5];
        transpose_k<<<dim3(64, 16), 256, 0, stream>>>(wq + l * TSZ, wqH, wqL, DM, HD);
        transpose_k<<<dim3(64, 16), 256, 0, stream>>>(wk + l * TSZ, wkH, wkL, DM, HD);
        transpose_k<<<dim3(64, 16), 256, 0, stream>>>(wv + l * TSZ, wvH, wvL, DM, HD);

        // ---- attention in two 2-batch halves (z = batch within half) ----
        for (int h2 = 0; h2 < 2; ++h2) {
            const long yofs = (long)(2 * h2) * SD;
            // q = y@wq + bq  (score-critical: always NP=3)
            gemm3_nt<4, true, 3><<<dim3(16, 32, 2), 256, 0, stream>>>(
                ybh + yofs, ybl + yofs, wqH, wqL, bq + l * HD, qh, ql,
                DM, HD, SD, 0, (long)SEQ * HD);
            // k = y@wk + bk
            gemm3_nt<4, true, 3><<<dim3(16, 32, 2), 256, 0, stream>>>(
                ybh + yofs, ybl + yofs, wkH, wkL, bk + l * HD, kh, kl,
                DM, HD, SD, 0, (long)SEQ * HD);
            // scores = q@k^T -> f32 (score-critical: always NP=3)
            gemm3_nt<0, false, 3><<<dim3(16, 16, 2), 256, 0, stream>>>(
                qh, ql, kh, kl, nullptr, scf, nullptr,
                HD, SEQ, (long)SEQ * HD, (long)SEQ * HD, (long)SEQ * SEQ);
            // softmax -> split probs (into dead q region)
            softmax_k<<<2 * SEQ, 256, 0, stream>>>(scf, pbh, pbl);
            // v = y@wv + bv, split transposed -> vT (layer 2: post-score, NP=1)
            if (l == 0)
                gemm3_nt<5, true, 3><<<dim3(16, 32, 2), 256, 0, stream>>>(
                    ybh + yofs, ybl + yofs, wvH, wvL, bv + l * HD, vTh, vTl,
                    DM, SEQ, SD, 0, (long)HD * SEQ);
            else
                gemm3_nt<5, true, 1><<<dim3(16, 32, 2), 256, 0, stream>>>(
                    ybh + yofs, nullptr, wvH, nullptr, bv + l * HD, vTh, vTl,
                    DM, SEQ, SD, 0, (long)HD * SEQ);
            // att = P@V -> split bf16 (layer 2: NP=1)
            if (l == 0)
                gemm3_nt<4, false, 3><<<dim3(16, 32, 2), 256, 0, stream>>>(
                    pbh, pbl, vTh, vTl, nullptr,
                    atth + yofs * 4, attl + yofs * 4,
                    SEQ, HD, (long)SEQ * SEQ, (long)HD * SEQ, (long)SEQ * HD);
            else
                gemm3_nt<4, false, 1><<<dim3(16, 32, 2), 256, 0, stream>>>(
                    pbh, nullptr, vTh, nullptr, nullptr,
                    atth + yofs * 4, attl + yofs * 4,
                    SEQ, HD, (long)SEQ * SEQ, (long)HD * SEQ, (long)SEQ * HD);
        }

        // ---- phase 2 weights: wo, w1, w2 (wq/wk/wv dead) ----
        bf16 *woH = slot[0], *woL = slot[1], *w1H = slot[2], *w1L = slot[3],
             *w2H = slot[4], *w2L = slot[5];
        transpose_k<<<dim3(16, 64), 256, 0, stream>>>(wo + l * TSZ, woH, woL, HD, DM);
        transpose_k<<<dim3(64, 16), 256, 0, stream>>>(w1 + l * TSZ, w1H, w1L, DM, HD);
        transpose_k<<<dim3(16, 64), 256, 0, stream>>>(w2 + l * TSZ, w2H, w2L, HD, DM);

        // attout = att@wo + bo -> f32 (layer 2: NP=1)
        if (l == 0)
            gemm3_nt<0, true, 3><<<dim3(64, 8, 1), 256, 0, stream>>>(
                atth, attl, woH, woL, bo + l * DM, attout, nullptr, HD, DM, 0, 0, 0);
        else
            gemm3_nt<0, true, 1><<<dim3(64, 8, 1), 256, 0, stream>>>(
                atth, nullptr, woH, nullptr, bo + l * DM, attout, nullptr, HD, DM, 0, 0, 0);
        // LN1(y + attout)
        ln_stats_k<<<dim3(64, NB), 256, 0, stream>>>(ybh, ybl, attout, part);
        ln_fin_k  <<<NB, 64, 0, stream>>>(part, stats);
        ln_apply_k<<<8192, 256, 0, stream>>>(ybh, ybl, attout,
                                             ln1w + (long)l * SD, ln1b + (long)l * SD,
                                             stats, ybh, ybl, nullptr);
        // h = y@w1 + b1 -> split bf16 (layer 2: NP=1)
        if (l == 0)
            gemm3_nt<4, true, 3><<<dim3(64, 32, 1), 256, 0, stream>>>(
                ybh, ybl, w1H, w1L, b1 + l * HD, hh, hl, DM, HD, 0, 0, 0);
        else
            gemm3_nt<4, true, 1><<<dim3(64, 32, 1), 256, 0, stream>>>(
                ybh, nullptr, w1H, nullptr, b1 + l * HD, hh, hl, DM, HD, 0, 0, 0);
        // ffn = gelu(h@w2 + b2) -> f32 (layer 2: NP=1)
        if (l == 0)
            gemm3_nt<1, true, 3><<<dim3(64, 8, 1), 256, 0, stream>>>(
                hh, hl, w2H, w2L, b2 + l * DM, ffnf, nullptr, HD, DM, 0, 0, 0);
        else
            gemm3_nt<1, true, 1><<<dim3(64, 8, 1), 256, 0, stream>>>(
                hh, nullptr, w2H, nullptr, b2 + l * DM, ffnf, nullptr, HD, DM, 0, 0, 0);
        // LN2(y + ffn); final layer also writes f32 to d_out
        float* fdst = (l == 1) ? (float*)d_out : nullptr;
        ln_stats_k<<<dim3(64, NB), 256, 0, stream>>>(ybh, ybl, ffnf, part);
        ln_fin_k  <<<NB, 64, 0, stream>>>(part, stats);
        ln_apply_k<<<8192, 256, 0, stream>>>(ybh, ybl, ffnf,
                                             ln2w + (long)l * SD, ln2b + (long)l * SD,
                                             stats, ybh, ybl, fdst);
    }
}

// Round 11
// 2410.565 us; speedup vs baseline: 1.9795x; 1.4200x over previous
//
#include <hip/hip_runtime.h>
#include <cstdint>
#include <cstddef>

using bf16 = __bf16;
typedef float f32x4 __attribute__((ext_vector_type(4)));
typedef bf16 bf16x8 __attribute__((ext_vector_type(8)));
typedef bf16 bf16x4 __attribute__((ext_vector_type(4)));

#define NB 4           // batch
#define SEQ 2048
#define DM 1024        // d_model
#define HD 4096        // hidden
#define SD (SEQ*DM)    // 2^21 elems per sample

__device__ __forceinline__ float geluf(float v) {
    return 0.5f * v * (1.0f + erff(v * 0.70710678118654752f));
}

#define GLL(gp, lp) __builtin_amdgcn_global_load_lds( \
    (const __attribute__((address_space(1))) void*)(gp), \
    (__attribute__((address_space(3))) void*)(lp), 16, 0, 0)

// ---------------------------------------------------------------------------
// Split-precision NT GEMM, fused NP-pass, single-buffered (R8/R10 proven
// structure: 2 blocks/CU implicit overlap):
//   NP=3: C = Ah*Bh + Al*Bh + Ah*Bl  (~17-bit mantissa, f32 accum)
//   NP=1: C = Ah*Bh                  (plain bf16; 32KB LDS -> 4 blocks/CU)
// A: M x K row-major bf16 (pair), Bt: N x K row-major bf16 (pair).
// ldab = row stride of A and B (== K except for K-split launches).
// Tile 128x128x64, 4 waves, 16x16x32 bf16 MFMA, global_load_lds staging,
// chunk XOR swizzle (c' = c ^ (m&7)) on BOTH global source and ds_read addr.
// EPI: 0 = f32 store, 1 = f32 gelu store,
//      4 = split bf16 (hi+lo) store, 5 = split bf16 transposed store (V^T)
// ---------------------------------------------------------------------------
template<int EPI, bool BIAS, int NP>
__global__ __launch_bounds__(256, NP == 1 ? 4 : 2) void gemm3_nt(
    const bf16* __restrict__ Ah, const bf16* __restrict__ Al,
    const bf16* __restrict__ Bh, const bf16* __restrict__ Bl,
    const float* __restrict__ bias, void* __restrict__ Cg, void* __restrict__ Cl,
    const int K, const int ldab, const int ldc,
    const long sA, const long sB, const long sC)
{
    constexpr int TILE = 128 * 64;                 // elems per plane
    constexpr int LOSZ = (NP == 3) ? TILE : 8;     // lo planes only for NP=3
    __shared__ __align__(16) bf16 smAh[TILE];
    __shared__ __align__(16) bf16 smBh[TILE];
    __shared__ __align__(16) bf16 smAl[LOSZ];
    __shared__ __align__(16) bf16 smBl[LOSZ];

    const int tid  = threadIdx.x;
    const int lane = tid & 63;
    const int wave = tid >> 6;
    const int wr   = (wave >> 1) << 6;
    const int wc   = (wave & 1) << 6;
    const int l15  = lane & 15;
    const int q4   = lane >> 4;

    const long aoff = (long)blockIdx.z * sA + (long)blockIdx.x * 128 * ldab;
    const long boff = (long)blockIdx.z * sB + (long)blockIdx.y * 128 * ldab;
    const bf16* pAh = Ah + aoff;
    const bf16* pAl = (NP == 3) ? Al + aoff : nullptr;
    const bf16* pBh = Bh + boff;
    const bf16* pBl = (NP == 3) ? Bl + boff : nullptr;

    // staging: chunk = it*256 + tid; row m = chunk>>3;
    // global chunk col = (chunk&7) ^ (m&7)  (pre-swizzled source)
    int srow[4], scol[4];
#pragma unroll
    for (int it = 0; it < 4; ++it) {
        int chunk = it * 256 + tid;
        int m = chunk >> 3;
        srow[it] = m;
        scol[it] = ((chunk & 7) ^ (m & 7)) * 8;
    }

    f32x4 acc[4][4] = {};

    for (int k0 = 0; k0 < K; k0 += 64) {
#pragma unroll
        for (int it = 0; it < 4; ++it) {
            const long go = (long)srow[it] * ldab + (k0 + scol[it]);
            const size_t lo = (size_t)(it * 256 + (wave << 6)) * 8;   // linear fill
            GLL(pAh + go, smAh + lo);
            if constexpr (NP == 3) GLL(pAl + go, smAl + lo);
            GLL(pBh + go, smBh + lo);
            if constexpr (NP == 3) GLL(pBl + go, smBl + lo);
        }
        __syncthreads();   // compiler drains vmcnt(0) before barrier

#pragma unroll
        for (int kk = 0; kk < 2; ++kk) {
            bf16x8 avh[4], avl[4], bvh[4], bvl[4];
#pragma unroll
            for (int i = 0; i < 4; ++i) {
                const int rowa = wr + i * 16 + l15;
                const int ca = ((kk * 4 + q4) ^ (rowa & 7)) * 8;   // swizzled read
                avh[i] = *(const bf16x8*)(smAh + rowa * 64 + ca);
                if constexpr (NP == 3) avl[i] = *(const bf16x8*)(smAl + rowa * 64 + ca);
                const int rowb = wc + i * 16 + l15;
                const int cb = ((kk * 4 + q4) ^ (rowb & 7)) * 8;
                bvh[i] = *(const bf16x8*)(smBh + rowb * 64 + cb);
                if constexpr (NP == 3) bvl[i] = *(const bf16x8*)(smBl + rowb * 64 + cb);
            }
#pragma unroll
            for (int i = 0; i < 4; ++i)
#pragma unroll
                for (int j = 0; j < 4; ++j) {
                    acc[i][j] = __builtin_amdgcn_mfma_f32_16x16x32_bf16(
                        avh[i], bvh[j], acc[i][j], 0, 0, 0);
                    if constexpr (NP == 3) {
                        acc[i][j] = __builtin_amdgcn_mfma_f32_16x16x32_bf16(
                            avl[i], bvh[j], acc[i][j], 0, 0, 0);
                        acc[i][j] = __builtin_amdgcn_mfma_f32_16x16x32_bf16(
                            avh[i], bvl[j], acc[i][j], 0, 0, 0);
                    }
                }
        }
        __syncthreads();
    }

    // epilogue: D col = lane&15, row = (lane>>4)*4 + e
    const long zC = (long)blockIdx.z * sC;
    const int gcol0 = blockIdx.y * 128 + wc + l15;
    const int grow0 = blockIdx.x * 128 + wr + q4 * 4;
#pragma unroll
    for (int j = 0; j < 4; ++j) {
        const int col = gcol0 + j * 16;
        const float bvz = BIAS ? bias[col] : 0.0f;
#pragma unroll
        for (int i = 0; i < 4; ++i) {
            const int row = grow0 + i * 16;
            if (EPI == 5) {
                bf16x4 oh, ol;
#pragma unroll
                for (int e = 0; e < 4; ++e) {
                    const float v = acc[i][j][e] + bvz;
                    const bf16 hi = (bf16)v;
                    oh[e] = hi;
                    ol[e] = (bf16)(v - (float)hi);
                }
                *(bf16x4*)((bf16*)Cg + zC + (long)col * ldc + row) = oh;
                *(bf16x4*)((bf16*)Cl + zC + (long)col * ldc + row) = ol;
            } else {
#pragma unroll
                for (int e = 0; e < 4; ++e) {
                    float v = acc[i][j][e] + bvz;
                    if (EPI == 1) v = geluf(v);
                    const long off = zC + (long)(row + e) * ldc + col;
                    if (EPI == 4) {
                        const bf16 hi = (bf16)v;
                        ((bf16*)Cg)[off] = hi;
                        ((bf16*)Cl)[off] = (bf16)(v - (float)hi);
                    } else {
                        ((float*)Cg)[off] = v;
                    }
                }
            }
        }
    }
}

// ---------------------------------------------------------------------------
// y = emb[x] (f32) + sinusoidal pos -> split bf16 (hi, lo) residual
// ---------------------------------------------------------------------------
__global__ __launch_bounds__(256) void embed_k(
    const int* __restrict__ x, const float* __restrict__ emb,
    bf16* __restrict__ yh, bf16* __restrict__ yl)
{
    const int bs = blockIdx.x;          // B*S
    const int s = bs & (SEQ - 1);
    const long e0 = (long)x[bs] * DM;
    const int d = threadIdx.x * 4;
    const float4 ev = *(const float4*)(emb + e0 + d);
    float o[4];
    const float fs = (float)s;
#pragma unroll
    for (int e = 0; e < 4; ++e) {
        const int dd = d + e;
        const float div = powf(10000.0f, (float)dd * (1.0f / 1024.0f));
        const float ang = fs / div;
        const float p = (dd & 1) ? cosf(ang) : sinf(ang);
        o[e] = ((const float*)&ev)[e] + p;
    }
    bf16x4 oh, ol;
#pragma unroll
    for (int e = 0; e < 4; ++e) {
        oh[e] = (bf16)o[e];
        ol[e] = (bf16)(o[e] - (float)oh[e]);
    }
    *(bf16x4*)(yh + (long)bs * DM + d) = oh;
    *(bf16x4*)(yl + (long)bs * DM + d) = ol;
}

// ---------------------------------------------------------------------------
// f32 -> split bf16 straight copy (for Wq, Wk used K-contiguous as-is)
// ---------------------------------------------------------------------------
__global__ __launch_bounds__(256) void copy_split_k(
    const float* __restrict__ src, bf16* __restrict__ dh, bf16* __restrict__ dl)
{
    const long i = ((long)blockIdx.x * 256 + threadIdx.x) * 4;
    const float4 v = *(const float4*)(src + i);
    const float vv[4] = {v.x, v.y, v.z, v.w};
    bf16x4 oh, ol;
#pragma unroll
    for (int e = 0; e < 4; ++e) {
        const bf16 hi = (bf16)vv[e];
        oh[e] = hi;
        ol[e] = (bf16)(vv[e] - (float)hi);
    }
    *(bf16x4*)(dh + i) = oh;
    *(bf16x4*)(dl + i) = ol;
}

// ---------------------------------------------------------------------------
// 4-plane f32 partial reduce -> split bf16 (for the K-split MT GEMM)
// ---------------------------------------------------------------------------
__global__ __launch_bounds__(256) void reduce4_k(
    const float* __restrict__ p, bf16* __restrict__ dh, bf16* __restrict__ dl)
{
    const long i = ((long)blockIdx.x * 256 + threadIdx.x) * 4;
    const long PL = (long)1 << 20;
    const float4 a = *(const float4*)(p + i);
    const float4 b = *(const float4*)(p + PL + i);
    const float4 c = *(const float4*)(p + 2 * PL + i);
    const float4 d = *(const float4*)(p + 3 * PL + i);
    const float vv[4] = {a.x + b.x + c.x + d.x, a.y + b.y + c.y + d.y,
                         a.z + b.z + c.z + d.z, a.w + b.w + c.w + d.w};
    bf16x4 oh, ol;
#pragma unroll
    for (int e = 0; e < 4; ++e) {
        const bf16 hi = (bf16)vv[e];
        oh[e] = hi;
        ol[e] = (bf16)(vv[e] - (float)hi);
    }
    *(bf16x4*)(dh + i) = oh;
    *(bf16x4*)(dl + i) = ol;
}

// ---------------------------------------------------------------------------
// f32 -> split bf16 transpose: src R x C (f32) -> dst C x R (hi, lo)
// ---------------------------------------------------------------------------
__global__ __launch_bounds__(256) void transpose_k(
    const float* __restrict__ src, bf16* __restrict__ dsth, bf16* __restrict__ dstl,
    int R, int C)
{
    __shared__ bf16 th[64][65];
    __shared__ bf16 tl[64][65];
    const int c0 = blockIdx.x * 64, r0 = blockIdx.y * 64;
    const int t = threadIdx.x;
    const int tr = t >> 4;
    const int tc = (t & 15) * 4;
#pragma unroll
    for (int p = 0; p < 4; ++p) {
        const int r = tr + p * 16;
        const float4 v = *(const float4*)(src + (long)(r0 + r) * C + c0 + tc);
        const float vv[4] = {v.x, v.y, v.z, v.w};
#pragma unroll
        for (int e = 0; e < 4; ++e) {
            const bf16 hi = (bf16)vv[e];
            th[r][tc + e] = hi;
            tl[r][tc + e] = (bf16)(vv[e] - (float)hi);
        }
    }
    __syncthreads();
#pragma unroll
    for (int p = 0; p < 4; ++p) {
        const int c = tr + p * 16;
        bf16x4 oh, ol;
#pragma unroll
        for (int e = 0; e < 4; ++e) { oh[e] = th[tc + e][c]; ol[e] = tl[tc + e][c]; }
        *(bf16x4*)(dsth + (long)(c0 + c) * R + r0 + tc) = oh;
        *(bf16x4*)(dstl + (long)(c0 + c) * R + r0 + tc) = ol;
    }
}

// ---------------------------------------------------------------------------
// wb[d] = sum_h W[d][h] * b[h]   (f32, W is [1024][4096])
// ---------------------------------------------------------------------------
__global__ __launch_bounds__(256) void matvec_wb_k(
    const float* __restrict__ W, const float* __restrict__ b, float* __restrict__ out)
{
    const int d = blockIdx.x;
    const int t = threadIdx.x;
    float s = 0.f;
    for (int h = t * 4; h < HD; h += 1024) {
        const float4 wv = *(const float4*)(W + (long)d * HD + h);
        const float4 bv = *(const float4*)(b + h);
        s += wv.x * bv.x + wv.y * bv.y + wv.z * bv.z + wv.w * bv.w;
    }
#pragma unroll
    for (int o = 32; o; o >>= 1) s += __shfl_xor(s, o);
    __shared__ float red[4];
    if ((t & 63) == 0) red[t >> 6] = s;
    __syncthreads();
    if (t == 0) out[d] = red[0] + red[1] + red[2] + red[3];
}

// ---------------------------------------------------------------------------
// v[r] = sum_d (yh+yl)[r][d] * w[d]   (key-side bias term for softmax)
// ---------------------------------------------------------------------------
__global__ __launch_bounds__(256) void matvec_v_k(
    const bf16* __restrict__ yh, const bf16* __restrict__ yl,
    const float* __restrict__ w, float* __restrict__ v)
{
    const long r = blockIdx.x;
    const int t = threadIdx.x;
    const bf16x4 h = *(const bf16x4*)(yh + r * DM + t * 4);
    const bf16x4 l = *(const bf16x4*)(yl + r * DM + t * 4);
    const float4 wv = *(const float4*)(w + t * 4);
    float s = ((float)h[0] + (float)l[0]) * wv.x + ((float)h[1] + (float)l[1]) * wv.y
            + ((float)h[2] + (float)l[2]) * wv.z + ((float)h[3] + (float)l[3]) * wv.w;
#pragma unroll
    for (int o = 32; o; o >>= 1) s += __shfl_xor(s, o);
    __shared__ float red[4];
    if ((t & 63) == 0) red[t >> 6] = s;
    __syncthreads();
    if (t == 0) v[r] = red[0] + red[1] + red[2] + red[3];
}

// ---------------------------------------------------------------------------
// Row softmax with key-side column bias: P = softmax(S[i][:] + v[:])
// 2048 f32 per row -> split bf16 (hi, lo)
// ---------------------------------------------------------------------------
__global__ __launch_bounds__(256) void softmax_k(
    const float* __restrict__ S, const float* __restrict__ v,
    bf16* __restrict__ Ph, bf16* __restrict__ Pl)
{
    const long row = blockIdx.x;
    const float4* src = (const float4*)(S + (row << 11));
    const float* vr = v + (long)(row >> 11) * SEQ;
    const int t = threadIdx.x;
    float4 a = src[t], b = src[256 + t];
    const float4 va = *(const float4*)(vr + t * 4);
    const float4 vb = *(const float4*)(vr + 1024 + t * 4);
    a.x += va.x; a.y += va.y; a.z += va.z; a.w += va.w;
    b.x += vb.x; b.y += vb.y; b.z += vb.z; b.w += vb.w;
    float m = fmaxf(fmaxf(fmaxf(a.x, a.y), fmaxf(a.z, a.w)),
                    fmaxf(fmaxf(b.x, b.y), fmaxf(b.z, b.w)));
#pragma unroll
    for (int o = 32; o; o >>= 1) m = fmaxf(m, __shfl_xor(m, o));
    __shared__ float red1[4], red2[4];
    const int wv = t >> 6;
    if ((t & 63) == 0) red1[wv] = m;
    __syncthreads();
    m = fmaxf(fmaxf(red1[0], red1[1]), fmaxf(red1[2], red1[3]));

    a.x = expf(a.x - m); a.y = expf(a.y - m); a.z = expf(a.z - m); a.w = expf(a.w - m);
    b.x = expf(b.x - m); b.y = expf(b.y - m); b.z = expf(b.z - m); b.w = expf(b.w - m);
    float s = a.x + a.y + a.z + a.w + b.x + b.y + b.z + b.w;
#pragma unroll
    for (int o = 32; o; o >>= 1) s += __shfl_xor(s, o);
    if ((t & 63) == 0) red2[wv] = s;
    __syncthreads();
    s = red2[0] + red2[1] + red2[2] + red2[3];
    const float inv = 1.0f / s;

    const float pv[8] = {a.x * inv, a.y * inv, a.z * inv, a.w * inv,
                         b.x * inv, b.y * inv, b.z * inv, b.w * inv};
    bf16x4 h0, l0, h1, l1;
#pragma unroll
    for (int e = 0; e < 4; ++e) {
        const bf16 hi = (bf16)pv[e];
        h0[e] = hi; l0[e] = (bf16)(pv[e] - (float)hi);
        const bf16 hj = (bf16)pv[4 + e];
        h1[e] = hj; l1[e] = (bf16)(pv[4 + e] - (float)hj);
    }
    *(bf16x4*)(Ph + (row << 11) + t * 4) = h0;
    *(bf16x4*)(Pl + (row << 11) + t * 4) = l0;
    *(bf16x4*)(Ph + (row << 11) + 1024 + t * 4) = h1;
    *(bf16x4*)(Pl + (row << 11) + 1024 + t * 4) = l1;
}

// ---------------------------------------------------------------------------
// LayerNorm over whole (S,D) sample; residual carried as split bf16 (hi+lo).
// ---------------------------------------------------------------------------
__global__ __launch_bounds__(256) void ln_stats_k(
    const bf16* __restrict__ yh, const bf16* __restrict__ yl,
    const float* __restrict__ r, float2* __restrict__ part)
{
    const int b = blockIdx.y;
    const long base = (long)b * SD + (long)blockIdx.x * (SD / 64);
    float s = 0.f, q = 0.f;
    for (int i = threadIdx.x; i < (SD / 64) / 4; i += 256) {
        const bf16x4 h = *(const bf16x4*)(yh + base + i * 4);
        const bf16x4 l = *(const bf16x4*)(yl + base + i * 4);
        const float4 c = *(const float4*)(r + base + i * 4);
        const float cc[4] = {c.x, c.y, c.z, c.w};
#pragma unroll
        for (int e = 0; e < 4; ++e) {
            const float x = (float)h[e] + (float)l[e] + cc[e];
            s += x; q += x * x;
        }
    }
#pragma unroll
    for (int o = 32; o; o >>= 1) { s += __shfl_xor(s, o); q += __shfl_xor(q, o); }
    __shared__ float rs[4], rq[4];
    const int wv = threadIdx.x >> 6;
    if ((threadIdx.x & 63) == 0) { rs[wv] = s; rq[wv] = q; }
    __syncthreads();
    if (threadIdx.x == 0)
        part[b * 64 + blockIdx.x] = make_float2(rs[0] + rs[1] + rs[2] + rs[3],
                                                rq[0] + rq[1] + rq[2] + rq[3]);
}

__global__ void ln_fin_k(const float2* __restrict__ part, float2* __restrict__ stats)
{
    const int b = blockIdx.x;
    const float2 p = part[b * 64 + threadIdx.x];
    float s = p.x, q = p.y;
#pragma unroll
    for (int o = 32; o; o >>= 1) { s += __shfl_xor(s, o); q += __shfl_xor(q, o); }
    if (threadIdx.x == 0) {
        const float inv_n = 1.0f / (float)SD;
        const float mean = s * inv_n;
        const float var = fmaxf(q * inv_n - mean * mean, 0.f);
        stats[b] = make_float2(mean, rsqrtf(var + 1e-5f));
    }
}

__global__ __launch_bounds__(256) void ln_apply_k(
    const bf16* __restrict__ yh_in, const bf16* __restrict__ yl_in,
    const float* __restrict__ r,
    const float* __restrict__ w, const float* __restrict__ bb,
    const float2* __restrict__ stats,
    bf16* __restrict__ yh_out, bf16* __restrict__ yl_out, float* __restrict__ fout)
{
    const long i = ((long)blockIdx.x * 256 + threadIdx.x) * 4;
    const int smp = (int)(i >> 21);
    const long sd = i & (SD - 1);
    const float2 st = stats[smp];
    const bf16x4 h = *(const bf16x4*)(yh_in + i);
    const bf16x4 l = *(const bf16x4*)(yl_in + i);
    const float4 c = *(const float4*)(r + i);
    const float4 wv = *(const float4*)(w + sd);
    const float4 bv = *(const float4*)(bb + sd);
    const float cc[4] = {c.x, c.y, c.z, c.w};
    const float ww[4] = {wv.x, wv.y, wv.z, wv.w};
    const float bbx[4] = {bv.x, bv.y, bv.z, bv.w};
    float o[4];
#pragma unroll
    for (int e = 0; e < 4; ++e) {
        const float x = (float)h[e] + (float)l[e] + cc[e];
        o[e] = (x - st.x) * st.y * ww[e] + bbx[e];
    }
    bf16x4 oh, ol;
#pragma unroll
    for (int e = 0; e < 4; ++e) {
        oh[e] = (bf16)o[e];
        ol[e] = (bf16)(o[e] - (float)oh[e]);
    }
    *(bf16x4*)(yh_out + i) = oh;
    *(bf16x4*)(yl_out + i) = ol;
    if (fout != nullptr) *(float4*)(fout + i) = *(float4*)o;
}

// ---------------------------------------------------------------------------
extern "C" void kernel_launch(void* const* d_in, const int* in_sizes, int n_in,
                              void* d_out, int out_size, void* d_ws, size_t ws_size,
                              hipStream_t stream)
{
    (void)in_sizes; (void)n_in; (void)out_size; (void)ws_size;

    const int*   x    = (const int*)  d_in[0];
    const float* emb  = (const float*)d_in[1];
    const float* wq   = (const float*)d_in[2];
    const float* bq   = (const float*)d_in[3];
    const float* wk   = (const float*)d_in[4];
    const float* bk   = (const float*)d_in[5];
    const float* wv   = (const float*)d_in[6];
    const float* bv   = (const float*)d_in[7];
    const float* wo   = (const float*)d_in[8];
    const float* bo   = (const float*)d_in[9];
    const float* w1   = (const float*)d_in[10];
    const float* b1   = (const float*)d_in[11];
    const float* w2   = (const float*)d_in[12];
    const float* b2   = (const float*)d_in[13];
    const float* ln1w = (const float*)d_in[14];
    const float* ln1b = (const float*)d_in[15];
    const float* ln2w = (const float*)d_in[16];
    const float* ln2b = (const float*)d_in[17];
    (void)bk;

    // Workspace — peak ~372.3 MiB (R2 proved ≥384 MiB usable; R3's 512 faulted).
    char* ws = (char*)d_ws;
    const size_t MB = (size_t)1 << 20;
    bf16*   ybh   = (bf16*) (ws);                  //  16 MiB residual hi
    bf16*   ybl   = (bf16*) (ws + 16  * MB);       //  16 MiB residual lo
    bf16*   wT    = (bf16*) (ws + 32  * MB);       //  48 MiB: 6 x 8 MiB weight slots
    bf16*   atth  = (bf16*) (ws + 80  * MB);       //  64 MiB att hi [8192][4096]
    bf16*   attl  = (bf16*) (ws + 144 * MB);       //  64 MiB att lo
    bf16*   zh    = (bf16*) (ws + 208 * MB);       //  16 MiB z hi [8192][1024]
    bf16*   zl    = (bf16*) (ws + 224 * MB);       //  16 MiB z lo
    float*  mtPart= (float*)(ws + 240 * MB);       //  16 MiB f32 [4][1024][1024] (transient)
    bf16*   vTh   = (bf16*) (ws + 240 * MB);       //  32 MiB V^T hi (per half, after MT reduce)
    bf16*   vTl   = (bf16*) (ws + 272 * MB);       //  32 MiB V^T lo
    float*  scf   = (float*)(ws + 304 * MB);       //  32 MiB f32 [2][2048][2048]
    bf16*   pbh   = (bf16*) (ws + 336 * MB);       //  16 MiB probs hi
    bf16*   pbl   = (bf16*) (ws + 352 * MB);       //  16 MiB probs lo
    float*  attout= (float*)(ws + 240 * MB);       //  32 MiB f32 (per-half region dead)
    float*  ffnf  = (float*)(ws + 240 * MB);       //  32 MiB f32
    bf16*   hh    = atth;                          //  64 MiB h hi (att dead after O-proj)
    bf16*   hl    = attl;                          //  64 MiB h lo
    bf16*   MTh   = (bf16*) (ws + 368 * MB);       //   2 MiB MT hi [1024][1024]
    bf16*   MTl   = (bf16*) (ws + 370 * MB);       //   2 MiB MT lo
    float*  wkbq  = (float*)(ws + 372 * MB);       //   4 KiB Wk·bq
    float*  vbias = (float*)(ws + 372 * MB + 65536);   //  32 KiB v = y·(Wk·bq)
    float2* part  = (float2*)(ws + 372 * MB + 131072); //  LN partials
    float2* stats = (float2*)(ws + 372 * MB + 196608);

    const long TSZ = (long)DM * HD;
    bf16* slot[6];
    for (int s = 0; s < 6; ++s) slot[s] = wT + (long)s * TSZ;

    embed_k<<<NB * SEQ, 256, 0, stream>>>(x, emb, ybh, ybl);

    for (int l = 0; l < 2; ++l) {
        // ---- phase 1 weights: wq, wk straight split copies; wv transposed ----
        bf16 *wqH = slot[0], *wqL = slot[1], *wkH = slot[2], *wkL = slot[3],
             *wvH = slot[4], *wvL = slot[5];
        copy_split_k<<<4096, 256, 0, stream>>>(wq + l * TSZ, wqH, wqL);
        copy_split_k<<<4096, 256, 0, stream>>>(wk + l * TSZ, wkH, wkL);
        transpose_k <<<dim3(64, 16), 256, 0, stream>>>(wv + l * TSZ, wvH, wvL, DM, HD);

        // ---- key-side bias term: v = y·(Wk·bq); row-constant terms cancel ----
        matvec_wb_k<<<1024, 256, 0, stream>>>(wk + l * TSZ, bq + l * HD, wkbq);
        matvec_v_k <<<NB * SEQ, 256, 0, stream>>>(ybh, ybl, wkbq, vbias);

        // ---- MT = Wk·Wq^T (K-split x4 -> f32 partials -> split bf16) ----
        gemm3_nt<0, false, 3><<<dim3(8, 8, 4), 256, 0, stream>>>(
            wkH, wkL, wqH, wqL, nullptr, mtPart, nullptr,
            1024, HD, DM, 1024, 1024, (long)1 << 20);
        reduce4_k<<<1024, 256, 0, stream>>>(mtPart, MTh, MTl);

        // ---- z = y·MT^T : [8192][1024] split bf16 ----
        gemm3_nt<4, false, 3><<<dim3(64, 8, 1), 256, 0, stream>>>(
            ybh, ybl, MTh, MTl, nullptr, zh, zl, DM, DM, DM, 0, 0, 0);

        // ---- attention in two 2-batch halves ----
        for (int h2 = 0; h2 < 2; ++h2) {
            const long yofs = (long)(2 * h2) * SD;
            // scores = z·y^T -> f32 [2][2048][2048]
            gemm3_nt<0, false, 3><<<dim3(16, 16, 2), 256, 0, stream>>>(
                zh + yofs, zl + yofs, ybh + yofs, ybl + yofs, nullptr, scf, nullptr,
                DM, DM, SEQ, (long)SD, (long)SD, (long)SEQ * SEQ);
            // softmax (+ key-side bias column) -> split probs
            softmax_k<<<2 * SEQ, 256, 0, stream>>>(scf, vbias + (long)(2 * h2) * SEQ, pbh, pbl);
            // v = y·Wv + bv, split transposed -> vT (layer 2: NP=1)
            if (l == 0)
                gemm3_nt<5, true, 3><<<dim3(16, 32, 2), 256, 0, stream>>>(
                    ybh + yofs, ybl + yofs, wvH, wvL, bv + l * HD, vTh, vTl,
                    DM, DM, SEQ, (long)SD, 0, (long)HD * SEQ);
            else
                gemm3_nt<5, true, 1><<<dim3(16, 32, 2), 256, 0, stream>>>(
                    ybh + yofs, nullptr, wvH, nullptr, bv + l * HD, vTh, vTl,
                    DM, DM, SEQ, (long)SD, 0, (long)HD * SEQ);
            // att = P@V (layer 2: NP=1)
            if (l == 0)
                gemm3_nt<4, false, 3><<<dim3(16, 32, 2), 256, 0, stream>>>(
                    pbh, pbl, vTh, vTl, nullptr,
                    atth + yofs * 4, attl + yofs * 4,
                    SEQ, SEQ, HD, (long)SEQ * SEQ, (long)HD * SEQ, (long)SEQ * HD);
            else
                gemm3_nt<4, false, 1><<<dim3(16, 32, 2), 256, 0, stream>>>(
                    pbh, nullptr, vTh, nullptr, nullptr,
                    atth + yofs * 4, attl + yofs * 4,
                    SEQ, SEQ, HD, (long)SEQ * SEQ, (long)HD * SEQ, (long)SEQ * HD);
        }

        // ---- phase 2 weights: wo, w1, w2 ----
        bf16 *woH = slot[0], *woL = slot[1], *w1H = slot[2], *w1L = slot[3],
             *w2H = slot[4], *w2L = slot[5];
        transpose_k<<<dim3(16, 64), 256, 0, stream>>>(wo + l * TSZ, woH, woL, HD, DM);
        transpose_k<<<dim3(64, 16), 256, 0, stream>>>(w1 + l * TSZ, w1H, w1L, DM, HD);
        transpose_k<<<dim3(16, 64), 256, 0, stream>>>(w2 + l * TSZ, w2H, w2L, HD, DM);

        // attout = att@wo + bo -> f32 (layer 2: NP=1)
        if (l == 0)
            gemm3_nt<0, true, 3><<<dim3(64, 8, 1), 256, 0, stream>>>(
                atth, attl, woH, woL, bo + l * DM, attout, nullptr, HD, HD, DM, 0, 0, 0);
        else
            gemm3_nt<0, true, 1><<<dim3(64, 8, 1), 256, 0, stream>>>(
                atth, nullptr, woH, nullptr, bo + l * DM, attout, nullptr, HD, HD, DM, 0, 0, 0);
        // LN1(y + attout)
        ln_stats_k<<<dim3(64, NB), 256, 0, stream>>>(ybh, ybl, attout, part);
        ln_fin_k  <<<NB, 64, 0, stream>>>(part, stats);
        ln_apply_k<<<8192, 256, 0, stream>>>(ybh, ybl, attout,
                                             ln1w + (long)l * SD, ln1b + (long)l * SD,
                                             stats, ybh, ybl, nullptr);
        // h = y@w1 + b1 -> split bf16 (layer 2: NP=1)
        if (l == 0)
            gemm3_nt<4, true, 3><<<dim3(64, 32, 1), 256, 0, stream>>>(
                ybh, ybl, w1H, w1L, b1 + l * HD, hh, hl, DM, DM, HD, 0, 0, 0);
        else
            gemm3_nt<4, true, 1><<<dim3(64, 32, 1), 256, 0, stream>>>(
                ybh, nullptr, w1H, nullptr, b1 + l * HD, hh, hl, DM, DM, HD, 0, 0, 0);
        // ffn = gelu(h@w2 + b2) -> f32 (layer 2: NP=1)
        if (l == 0)
            gemm3_nt<1, true, 3><<<dim3(64, 8, 1), 256, 0, stream>>>(
                hh, hl, w2H, w2L, b2 + l * DM, ffnf, nullptr, HD, HD, DM, 0, 0, 0);
        else
            gemm3_nt<1, true, 1><<<dim3(64, 8, 1), 256, 0, stream>>>(
                hh, nullptr, w2H, nullptr, b2 + l * DM, ffnf, nullptr, HD, HD, DM, 0, 0, 0);
        // LN2(y + ffn); final layer also writes f32 to d_out
        float* fdst = (l == 1) ? (float*)d_out : nullptr;
        ln_stats_k<<<dim3(64, NB), 256, 0, stream>>>(ybh, ybl, ffnf, part);
        ln_fin_k  <<<NB, 64, 0, stream>>>(part, stats);
        ln_apply_k<<<8192, 256, 0, stream>>>(ybh, ybl, ffnf,
                                             ln2w + (long)l * SD, ln2b + (long)l * SD,
                                             stats, ybh, ybl, fdst);
    }
}

// Round 12
// 1216.350 us; speedup vs baseline: 3.9230x; 1.9818x over previous
//
#include <hip/hip_runtime.h>
#include <cstdint>
#include <cstddef>

using bf16 = __bf16;
typedef float f32x4 __attribute__((ext_vector_type(4)));
typedef bf16 bf16x8 __attribute__((ext_vector_type(8)));
typedef bf16 bf16x4 __attribute__((ext_vector_type(4)));

#define NB 4           // batch
#define SEQ 2048
#define DM 1024        // d_model
#define HD 4096        // hidden
#define SD (SEQ*DM)    // 2^21 elems per sample

__device__ __forceinline__ float geluf(float v) {
    return 0.5f * v * (1.0f + erff(v * 0.70710678118654752f));
}

#define GLL(gp, lp) __builtin_amdgcn_global_load_lds( \
    (const __attribute__((address_space(1))) void*)(gp), \
    (__attribute__((address_space(3))) void*)(lp), 16, 0, 0)

// ---------------------------------------------------------------------------
// Split-precision NT GEMM, fused NP-pass, single-buffered (R8/R10/R11 proven
// structure: 2 blocks/CU implicit overlap):
//   NP=3: C = Ah*Bh + Al*Bh + Ah*Bl  (~17-bit mantissa, f32 accum)
//   NP=1: C = Ah*Bh                  (plain bf16; 32KB LDS -> 4 blocks/CU)
// A: M x K row-major bf16 (pair), Bt: N x K row-major bf16 (pair).
// ldab = row stride of A and B (== K except for K-split launches).
// Tile 128x128x64, 4 waves, 16x16x32 bf16 MFMA, global_load_lds staging,
// chunk XOR swizzle (c' = c ^ (m&7)) on BOTH global source and ds_read addr.
// EPI: 0 = f32 store, 1 = f32 gelu store,
//      4 = split bf16 (hi+lo) store, 5 = split bf16 transposed store
// ---------------------------------------------------------------------------
template<int EPI, bool BIAS, int NP>
__global__ __launch_bounds__(256, NP == 1 ? 4 : 2) void gemm3_nt(
    const bf16* __restrict__ Ah, const bf16* __restrict__ Al,
    const bf16* __restrict__ Bh, const bf16* __restrict__ Bl,
    const float* __restrict__ bias, void* __restrict__ Cg, void* __restrict__ Cl,
    const int K, const int ldab, const int ldc,
    const long sA, const long sB, const long sC)
{
    constexpr int TILE = 128 * 64;                 // elems per plane
    constexpr int LOSZ = (NP == 3) ? TILE : 8;     // lo planes only for NP=3
    __shared__ __align__(16) bf16 smAh[TILE];
    __shared__ __align__(16) bf16 smBh[TILE];
    __shared__ __align__(16) bf16 smAl[LOSZ];
    __shared__ __align__(16) bf16 smBl[LOSZ];

    const int tid  = threadIdx.x;
    const int lane = tid & 63;
    const int wave = tid >> 6;
    const int wr   = (wave >> 1) << 6;
    const int wc   = (wave & 1) << 6;
    const int l15  = lane & 15;
    const int q4   = lane >> 4;

    const long aoff = (long)blockIdx.z * sA + (long)blockIdx.x * 128 * ldab;
    const long boff = (long)blockIdx.z * sB + (long)blockIdx.y * 128 * ldab;
    const bf16* pAh = Ah + aoff;
    const bf16* pAl = (NP == 3) ? Al + aoff : nullptr;
    const bf16* pBh = Bh + boff;
    const bf16* pBl = (NP == 3) ? Bl + boff : nullptr;

    // staging: chunk = it*256 + tid; row m = chunk>>3;
    // global chunk col = (chunk&7) ^ (m&7)  (pre-swizzled source)
    int srow[4], scol[4];
#pragma unroll
    for (int it = 0; it < 4; ++it) {
        int chunk = it * 256 + tid;
        int m = chunk >> 3;
        srow[it] = m;
        scol[it] = ((chunk & 7) ^ (m & 7)) * 8;
    }

    f32x4 acc[4][4] = {};

    for (int k0 = 0; k0 < K; k0 += 64) {
#pragma unroll
        for (int it = 0; it < 4; ++it) {
            const long go = (long)srow[it] * ldab + (k0 + scol[it]);
            const size_t lo = (size_t)(it * 256 + (wave << 6)) * 8;   // linear fill
            GLL(pAh + go, smAh + lo);
            if constexpr (NP == 3) GLL(pAl + go, smAl + lo);
            GLL(pBh + go, smBh + lo);
            if constexpr (NP == 3) GLL(pBl + go, smBl + lo);
        }
        __syncthreads();   // compiler drains vmcnt(0) before barrier

#pragma unroll
        for (int kk = 0; kk < 2; ++kk) {
            bf16x8 avh[4], avl[4], bvh[4], bvl[4];
#pragma unroll
            for (int i = 0; i < 4; ++i) {
                const int rowa = wr + i * 16 + l15;
                const int ca = ((kk * 4 + q4) ^ (rowa & 7)) * 8;   // swizzled read
                avh[i] = *(const bf16x8*)(smAh + rowa * 64 + ca);
                if constexpr (NP == 3) avl[i] = *(const bf16x8*)(smAl + rowa * 64 + ca);
                const int rowb = wc + i * 16 + l15;
                const int cb = ((kk * 4 + q4) ^ (rowb & 7)) * 8;
                bvh[i] = *(const bf16x8*)(smBh + rowb * 64 + cb);
                if constexpr (NP == 3) bvl[i] = *(const bf16x8*)(smBl + rowb * 64 + cb);
            }
#pragma unroll
            for (int i = 0; i < 4; ++i)
#pragma unroll
                for (int j = 0; j < 4; ++j) {
                    acc[i][j] = __builtin_amdgcn_mfma_f32_16x16x32_bf16(
                        avh[i], bvh[j], acc[i][j], 0, 0, 0);
                    if constexpr (NP == 3) {
                        acc[i][j] = __builtin_amdgcn_mfma_f32_16x16x32_bf16(
                            avl[i], bvh[j], acc[i][j], 0, 0, 0);
                        acc[i][j] = __builtin_amdgcn_mfma_f32_16x16x32_bf16(
                            avh[i], bvl[j], acc[i][j], 0, 0, 0);
                    }
                }
        }
        __syncthreads();
    }

    // epilogue: D col = lane&15, row = (lane>>4)*4 + e
    const long zC = (long)blockIdx.z * sC;
    const int gcol0 = blockIdx.y * 128 + wc + l15;
    const int grow0 = blockIdx.x * 128 + wr + q4 * 4;
#pragma unroll
    for (int j = 0; j < 4; ++j) {
        const int col = gcol0 + j * 16;
        const float bvz = BIAS ? bias[col] : 0.0f;
#pragma unroll
        for (int i = 0; i < 4; ++i) {
            const int row = grow0 + i * 16;
            if (EPI == 5) {
                bf16x4 oh, ol;
#pragma unroll
                for (int e = 0; e < 4; ++e) {
                    const float v = acc[i][j][e] + bvz;
                    const bf16 hi = (bf16)v;
                    oh[e] = hi;
                    ol[e] = (bf16)(v - (float)hi);
                }
                *(bf16x4*)((bf16*)Cg + zC + (long)col * ldc + row) = oh;
                *(bf16x4*)((bf16*)Cl + zC + (long)col * ldc + row) = ol;
            } else {
#pragma unroll
                for (int e = 0; e < 4; ++e) {
                    float v = acc[i][j][e] + bvz;
                    if (EPI == 1) v = geluf(v);
                    const long off = zC + (long)(row + e) * ldc + col;
                    if (EPI == 4) {
                        const bf16 hi = (bf16)v;
                        ((bf16*)Cg)[off] = hi;
                        ((bf16*)Cl)[off] = (bf16)(v - (float)hi);
                    } else {
                        ((float*)Cg)[off] = v;
                    }
                }
            }
        }
    }
}

// ---------------------------------------------------------------------------
// y = emb[x] (f32) + sinusoidal pos -> split bf16 (hi, lo) residual
// ---------------------------------------------------------------------------
__global__ __launch_bounds__(256) void embed_k(
    const int* __restrict__ x, const float* __restrict__ emb,
    bf16* __restrict__ yh, bf16* __restrict__ yl)
{
    const int bs = blockIdx.x;          // B*S
    const int s = bs & (SEQ - 1);
    const long e0 = (long)x[bs] * DM;
    const int d = threadIdx.x * 4;
    const float4 ev = *(const float4*)(emb + e0 + d);
    float o[4];
    const float fs = (float)s;
#pragma unroll
    for (int e = 0; e < 4; ++e) {
        const int dd = d + e;
        const float div = powf(10000.0f, (float)dd * (1.0f / 1024.0f));
        const float ang = fs / div;
        const float p = (dd & 1) ? cosf(ang) : sinf(ang);
        o[e] = ((const float*)&ev)[e] + p;
    }
    bf16x4 oh, ol;
#pragma unroll
    for (int e = 0; e < 4; ++e) {
        oh[e] = (bf16)o[e];
        ol[e] = (bf16)(o[e] - (float)oh[e]);
    }
    *(bf16x4*)(yh + (long)bs * DM + d) = oh;
    *(bf16x4*)(yl + (long)bs * DM + d) = ol;
}

// ---------------------------------------------------------------------------
// f32 -> split bf16 straight copy (weights used K-contiguous as-is)
// ---------------------------------------------------------------------------
__global__ __launch_bounds__(256) void copy_split_k(
    const float* __restrict__ src, bf16* __restrict__ dh, bf16* __restrict__ dl)
{
    const long i = ((long)blockIdx.x * 256 + threadIdx.x) * 4;
    const float4 v = *(const float4*)(src + i);
    const float vv[4] = {v.x, v.y, v.z, v.w};
    bf16x4 oh, ol;
#pragma unroll
    for (int e = 0; e < 4; ++e) {
        const bf16 hi = (bf16)vv[e];
        oh[e] = hi;
        ol[e] = (bf16)(vv[e] - (float)hi);
    }
    *(bf16x4*)(dh + i) = oh;
    *(bf16x4*)(dl + i) = ol;
}

// ---------------------------------------------------------------------------
// 8-plane f32 partial reduce -> split bf16 (MT) or f32 (W_vo/W_12 pre-transp.)
// ---------------------------------------------------------------------------
__global__ __launch_bounds__(256) void reduce8s_k(
    const float* __restrict__ p, bf16* __restrict__ dh, bf16* __restrict__ dl)
{
    const long i = ((long)blockIdx.x * 256 + threadIdx.x) * 4;
    const long PL = (long)1 << 20;
    float vv[4] = {0.f, 0.f, 0.f, 0.f};
#pragma unroll
    for (int q = 0; q < 8; ++q) {
        const float4 a = *(const float4*)(p + q * PL + i);
        vv[0] += a.x; vv[1] += a.y; vv[2] += a.z; vv[3] += a.w;
    }
    bf16x4 oh, ol;
#pragma unroll
    for (int e = 0; e < 4; ++e) {
        const bf16 hi = (bf16)vv[e];
        oh[e] = hi;
        ol[e] = (bf16)(vv[e] - (float)hi);
    }
    *(bf16x4*)(dh + i) = oh;
    *(bf16x4*)(dl + i) = ol;
}

__global__ __launch_bounds__(256) void reduce8f_k(
    const float* __restrict__ p, float* __restrict__ dst)
{
    const long i = ((long)blockIdx.x * 256 + threadIdx.x) * 4;
    const long PL = (long)1 << 20;
    float vv[4] = {0.f, 0.f, 0.f, 0.f};
#pragma unroll
    for (int q = 0; q < 8; ++q) {
        const float4 a = *(const float4*)(p + q * PL + i);
        vv[0] += a.x; vv[1] += a.y; vv[2] += a.z; vv[3] += a.w;
    }
    *(float4*)(dst + i) = *(float4*)vv;
}

// ---------------------------------------------------------------------------
// f32 -> split bf16 transpose: src R x C (f32) -> dst C x R (hi, lo)
// ---------------------------------------------------------------------------
__global__ __launch_bounds__(256) void transpose_k(
    const float* __restrict__ src, bf16* __restrict__ dsth, bf16* __restrict__ dstl,
    int R, int C)
{
    __shared__ bf16 th[64][65];
    __shared__ bf16 tl[64][65];
    const int c0 = blockIdx.x * 64, r0 = blockIdx.y * 64;
    const int t = threadIdx.x;
    const int tr = t >> 4;
    const int tc = (t & 15) * 4;
#pragma unroll
    for (int p = 0; p < 4; ++p) {
        const int r = tr + p * 16;
        const float4 v = *(const float4*)(src + (long)(r0 + r) * C + c0 + tc);
        const float vv[4] = {v.x, v.y, v.z, v.w};
#pragma unroll
        for (int e = 0; e < 4; ++e) {
            const bf16 hi = (bf16)vv[e];
            th[r][tc + e] = hi;
            tl[r][tc + e] = (bf16)(vv[e] - (float)hi);
        }
    }
    __syncthreads();
#pragma unroll
    for (int p = 0; p < 4; ++p) {
        const int c = tr + p * 16;
        bf16x4 oh, ol;
#pragma unroll
        for (int e = 0; e < 4; ++e) { oh[e] = th[tc + e][c]; ol[e] = tl[tc + e][c]; }
        *(bf16x4*)(dsth + (long)(c0 + c) * R + r0 + tc) = oh;
        *(bf16x4*)(dstl + (long)(c0 + c) * R + r0 + tc) = ol;
    }
}

// ---------------------------------------------------------------------------
// wb[d] = sum_h W[d][h] * b[h]   (f32, W is [1024][4096])
// ---------------------------------------------------------------------------
__global__ __launch_bounds__(256) void matvec_wb_k(
    const float* __restrict__ W, const float* __restrict__ b, float* __restrict__ out)
{
    const int d = blockIdx.x;
    const int t = threadIdx.x;
    float s = 0.f;
    for (int h = t * 4; h < HD; h += 1024) {
        const float4 wv = *(const float4*)(W + (long)d * HD + h);
        const float4 bv = *(const float4*)(b + h);
        s += wv.x * bv.x + wv.y * bv.y + wv.z * bv.z + wv.w * bv.w;
    }
#pragma unroll
    for (int o = 32; o; o >>= 1) s += __shfl_xor(s, o);
    __shared__ float red[4];
    if ((t & 63) == 0) red[t >> 6] = s;
    __syncthreads();
    if (t == 0) out[d] = red[0] + red[1] + red[2] + red[3];
}

// ---------------------------------------------------------------------------
// out[j] = sum_h (BtH+BtL)[j][h] * b[h] + add[j]   (Bt split [1024][4096])
// ---------------------------------------------------------------------------
__global__ __launch_bounds__(256) void matvec_bt_k(
    const bf16* __restrict__ bth, const bf16* __restrict__ btl,
    const float* __restrict__ b, const float* __restrict__ add,
    float* __restrict__ out)
{
    const int j = blockIdx.x;
    const int t = threadIdx.x;
    float s = 0.f;
    for (int h = t * 4; h < HD; h += 1024) {
        const bf16x4 hx = *(const bf16x4*)(bth + (long)j * HD + h);
        const bf16x4 lx = *(const bf16x4*)(btl + (long)j * HD + h);
        const float4 bv = *(const float4*)(b + h);
        s += ((float)hx[0] + (float)lx[0]) * bv.x + ((float)hx[1] + (float)lx[1]) * bv.y
           + ((float)hx[2] + (float)lx[2]) * bv.z + ((float)hx[3] + (float)lx[3]) * bv.w;
    }
#pragma unroll
    for (int o = 32; o; o >>= 1) s += __shfl_xor(s, o);
    __shared__ float red[4];
    if ((t & 63) == 0) red[t >> 6] = s;
    __syncthreads();
    if (t == 0) out[j] = s * 0.f + red[0] + red[1] + red[2] + red[3] + add[j];
}

// ---------------------------------------------------------------------------
// v[r] = sum_d (yh+yl)[r][d] * w[d]   (key-side bias term for softmax)
// ---------------------------------------------------------------------------
__global__ __launch_bounds__(256) void matvec_v_k(
    const bf16* __restrict__ yh, const bf16* __restrict__ yl,
    const float* __restrict__ w, float* __restrict__ v)
{
    const long r = blockIdx.x;
    const int t = threadIdx.x;
    const bf16x4 h = *(const bf16x4*)(yh + r * DM + t * 4);
    const bf16x4 l = *(const bf16x4*)(yl + r * DM + t * 4);
    const float4 wv = *(const float4*)(w + t * 4);
    float s = ((float)h[0] + (float)l[0]) * wv.x + ((float)h[1] + (float)l[1]) * wv.y
            + ((float)h[2] + (float)l[2]) * wv.z + ((float)h[3] + (float)l[3]) * wv.w;
#pragma unroll
    for (int o = 32; o; o >>= 1) s += __shfl_xor(s, o);
    __shared__ float red[4];
    if ((t & 63) == 0) red[t >> 6] = s;
    __syncthreads();
    if (t == 0) v[r] = red[0] + red[1] + red[2] + red[3];
}

// ---------------------------------------------------------------------------
// Row softmax with key-side column bias: P = softmax(S[i][:] + v[:])
// 2048 f32 per row -> split bf16 (hi, lo)
// ---------------------------------------------------------------------------
__global__ __launch_bounds__(256) void softmax_k(
    const float* __restrict__ S, const float* __restrict__ v,
    bf16* __restrict__ Ph, bf16* __restrict__ Pl)
{
    const long row = blockIdx.x;
    const float4* src = (const float4*)(S + (row << 11));
    const float* vr = v + (long)(row >> 11) * SEQ;
    const int t = threadIdx.x;
    float4 a = src[t], b = src[256 + t];
    const float4 va = *(const float4*)(vr + t * 4);
    const float4 vb = *(const float4*)(vr + 1024 + t * 4);
    a.x += va.x; a.y += va.y; a.z += va.z; a.w += va.w;
    b.x += vb.x; b.y += vb.y; b.z += vb.z; b.w += vb.w;
    float m = fmaxf(fmaxf(fmaxf(a.x, a.y), fmaxf(a.z, a.w)),
                    fmaxf(fmaxf(b.x, b.y), fmaxf(b.z, b.w)));
#pragma unroll
    for (int o = 32; o; o >>= 1) m = fmaxf(m, __shfl_xor(m, o));
    __shared__ float red1[4], red2[4];
    const int wv = t >> 6;
    if ((t & 63) == 0) red1[wv] = m;
    __syncthreads();
    m = fmaxf(fmaxf(red1[0], red1[1]), fmaxf(red1[2], red1[3]));

    a.x = expf(a.x - m); a.y = expf(a.y - m); a.z = expf(a.z - m); a.w = expf(a.w - m);
    b.x = expf(b.x - m); b.y = expf(b.y - m); b.z = expf(b.z - m); b.w = expf(b.w - m);
    float s = a.x + a.y + a.z + a.w + b.x + b.y + b.z + b.w;
#pragma unroll
    for (int o = 32; o; o >>= 1) s += __shfl_xor(s, o);
    if ((t & 63) == 0) red2[wv] = s;
    __syncthreads();
    s = red2[0] + red2[1] + red2[2] + red2[3];
    const float inv = 1.0f / s;

    const float pv[8] = {a.x * inv, a.y * inv, a.z * inv, a.w * inv,
                         b.x * inv, b.y * inv, b.z * inv, b.w * inv};
    bf16x4 h0, l0, h1, l1;
#pragma unroll
    for (int e = 0; e < 4; ++e) {
        const bf16 hi = (bf16)pv[e];
        h0[e] = hi; l0[e] = (bf16)(pv[e] - (float)hi);
        const bf16 hj = (bf16)pv[4 + e];
        h1[e] = hj; l1[e] = (bf16)(pv[4 + e] - (float)hj);
    }
    *(bf16x4*)(Ph + (row << 11) + t * 4) = h0;
    *(bf16x4*)(Pl + (row << 11) + t * 4) = l0;
    *(bf16x4*)(Ph + (row << 11) + 1024 + t * 4) = h1;
    *(bf16x4*)(Pl + (row << 11) + 1024 + t * 4) = l1;
}

// ---------------------------------------------------------------------------
// LayerNorm over whole (S,D) sample; residual carried as split bf16 (hi+lo).
// ---------------------------------------------------------------------------
__global__ __launch_bounds__(256) void ln_stats_k(
    const bf16* __restrict__ yh, const bf16* __restrict__ yl,
    const float* __restrict__ r, float2* __restrict__ part)
{
    const int b = blockIdx.y;
    const long base = (long)b * SD + (long)blockIdx.x * (SD / 64);
    float s = 0.f, q = 0.f;
    for (int i = threadIdx.x; i < (SD / 64) / 4; i += 256) {
        const bf16x4 h = *(const bf16x4*)(yh + base + i * 4);
        const bf16x4 l = *(const bf16x4*)(yl + base + i * 4);
        const float4 c = *(const float4*)(r + base + i * 4);
        const float cc[4] = {c.x, c.y, c.z, c.w};
#pragma unroll
        for (int e = 0; e < 4; ++e) {
            const float x = (float)h[e] + (float)l[e] + cc[e];
            s += x; q += x * x;
        }
    }
#pragma unroll
    for (int o = 32; o; o >>= 1) { s += __shfl_xor(s, o); q += __shfl_xor(q, o); }
    __shared__ float rs[4], rq[4];
    const int wv = threadIdx.x >> 6;
    if ((threadIdx.x & 63) == 0) { rs[wv] = s; rq[wv] = q; }
    __syncthreads();
    if (threadIdx.x == 0)
        part[b * 64 + blockIdx.x] = make_float2(rs[0] + rs[1] + rs[2] + rs[3],
                                                rq[0] + rq[1] + rq[2] + rq[3]);
}

__global__ void ln_fin_k(const float2* __restrict__ part, float2* __restrict__ stats)
{
    const int b = blockIdx.x;
    const float2 p = part[b * 64 + threadIdx.x];
    float s = p.x, q = p.y;
#pragma unroll
    for (int o = 32; o; o >>= 1) { s += __shfl_xor(s, o); q += __shfl_xor(q, o); }
    if (threadIdx.x == 0) {
        const float inv_n = 1.0f / (float)SD;
        const float mean = s * inv_n;
        const float var = fmaxf(q * inv_n - mean * mean, 0.f);
        stats[b] = make_float2(mean, rsqrtf(var + 1e-5f));
    }
}

__global__ __launch_bounds__(256) void ln_apply_k(
    const bf16* __restrict__ yh_in, const bf16* __restrict__ yl_in,
    const float* __restrict__ r,
    const float* __restrict__ w, const float* __restrict__ bb,
    const float2* __restrict__ stats,
    bf16* __restrict__ yh_out, bf16* __restrict__ yl_out, float* __restrict__ fout)
{
    const long i = ((long)blockIdx.x * 256 + threadIdx.x) * 4;
    const int smp = (int)(i >> 21);
    const long sd = i & (SD - 1);
    const float2 st = stats[smp];
    const bf16x4 h = *(const bf16x4*)(yh_in + i);
    const bf16x4 l = *(const bf16x4*)(yl_in + i);
    const float4 c = *(const float4*)(r + i);
    const float4 wv = *(const float4*)(w + sd);
    const float4 bv = *(const float4*)(bb + sd);
    const float cc[4] = {c.x, c.y, c.z, c.w};
    const float ww[4] = {wv.x, wv.y, wv.z, wv.w};
    const float bbx[4] = {bv.x, bv.y, bv.z, bv.w};
    float o[4];
#pragma unroll
    for (int e = 0; e < 4; ++e) {
        const float x = (float)h[e] + (float)l[e] + cc[e];
        o[e] = (x - st.x) * st.y * ww[e] + bbx[e];
    }
    bf16x4 oh, ol;
#pragma unroll
    for (int e = 0; e < 4; ++e) {
        oh[e] = (bf16)o[e];
        ol[e] = (bf16)(o[e] - (float)oh[e]);
    }
    *(bf16x4*)(yh_out + i) = oh;
    *(bf16x4*)(yl_out + i) = ol;
    if (fout != nullptr) *(float4*)(fout + i) = *(float4*)o;
}

// ---------------------------------------------------------------------------
extern "C" void kernel_launch(void* const* d_in, const int* in_sizes, int n_in,
                              void* d_out, int out_size, void* d_ws, size_t ws_size,
                              hipStream_t stream)
{
    (void)in_sizes; (void)n_in; (void)out_size; (void)ws_size;

    const int*   x    = (const int*)  d_in[0];
    const float* emb  = (const float*)d_in[1];
    const float* wq   = (const float*)d_in[2];
    const float* bq   = (const float*)d_in[3];
    const float* wk   = (const float*)d_in[4];
    const float* bk   = (const float*)d_in[5];
    const float* wv   = (const float*)d_in[6];
    const float* bv   = (const float*)d_in[7];
    const float* wo   = (const float*)d_in[8];
    const float* bo   = (const float*)d_in[9];
    const float* w1   = (const float*)d_in[10];
    const float* b1   = (const float*)d_in[11];
    const float* w2   = (const float*)d_in[12];
    const float* b2   = (const float*)d_in[13];
    const float* ln1w = (const float*)d_in[14];
    const float* ln1b = (const float*)d_in[15];
    const float* ln2w = (const float*)d_in[16];
    const float* ln2b = (const float*)d_in[17];
    (void)bk;   // cancels in softmax (row-constant)

    // Workspace — peak 352 MiB (R2 proved ≥384 MiB usable; R3's 512 faulted).
    char* ws = (char*)d_ws;
    const size_t MB = (size_t)1 << 20;
    bf16*   ybh   = (bf16*) (ws);                  //  16 MiB residual hi
    bf16*   ybl   = (bf16*) (ws + 16  * MB);       //  16 MiB residual lo
    bf16*   S0h   = (bf16*) (ws + 32  * MB);       //   8 MiB weight slot 0 hi
    bf16*   S0l   = (bf16*) (ws + 40  * MB);       //   8 MiB weight slot 0 lo
    bf16*   S1h   = (bf16*) (ws + 48  * MB);       //   8 MiB weight slot 1 hi
    bf16*   S1l   = (bf16*) (ws + 56  * MB);       //   8 MiB weight slot 1 lo
    bf16*   MTh   = (bf16*) (ws + 64  * MB);       //   2 MiB MT hi
    bf16*   MTl   = (bf16*) (ws + 66  * MB);       //   2 MiB MT lo
    bf16*   VOh   = (bf16*) (ws + 68  * MB);       //   2 MiB W_vo^T hi
    bf16*   VOl   = (bf16*) (ws + 70  * MB);       //   2 MiB W_vo^T lo
    bf16*   W12h  = (bf16*) (ws + 72  * MB);       //   2 MiB W_12^T hi
    bf16*   W12l  = (bf16*) (ws + 74  * MB);       //   2 MiB W_12^T lo
    float*  wkbq  = (float*)(ws + 76  * MB);                //  4 KiB
    float*  c_vo  = (float*)(ws + 76  * MB + 0x10000);      //  4 KiB
    float*  c_12  = (float*)(ws + 76  * MB + 0x20000);      //  4 KiB
    float*  vbias = (float*)(ws + 76  * MB + 0x30000);      // 32 KiB
    float2* part  = (float2*)(ws + 76 * MB + 0x40000);
    float2* stats = (float2*)(ws + 76 * MB + 0x50000);
    float*  wtmp8 = (float*)(ws + 80  * MB);       //  32 MiB K-split f32 partials
    float*  wtmpR = (float*)(ws + 112 * MB);       //   4 MiB reduced f32 [1024][1024]
    bf16*   zh    = (bf16*) (ws + 128 * MB);       //  16 MiB z hi [8192][1024]
    bf16*   zl    = (bf16*) (ws + 144 * MB);       //  16 MiB z lo
    bf16*   uTh   = (bf16*) (ws + 160 * MB);       //  16 MiB u^T hi [4][1024][2048]
    bf16*   uTl   = (bf16*) (ws + 176 * MB);       //  16 MiB u^T lo
    float*  scf   = (float*)(ws + 192 * MB);       //  64 MiB scores f32 [4][2048][2048]
    bf16*   pbh   = (bf16*) (ws + 256 * MB);       //  32 MiB probs hi
    bf16*   pbl   = (bf16*) (ws + 288 * MB);       //  32 MiB probs lo
    float*  attout= (float*)(ws + 320 * MB);       //  32 MiB f32 [8192][1024]
    float*  ffnf  = attout;                        //  (attout dead after LN1)

    const long TSZ = (long)DM * HD;

    embed_k<<<NB * SEQ, 256, 0, stream>>>(x, emb, ybh, ybl);

    for (int l = 0; l < 2; ++l) {
        // ================= score path (always NP=3) =================
        // wq, wk: straight split copies (used K-contiguous as-is)
        copy_split_k<<<4096, 256, 0, stream>>>(wq + l * TSZ, S0h, S0l);
        copy_split_k<<<4096, 256, 0, stream>>>(wk + l * TSZ, S1h, S1l);
        // key-side bias: vbias = y·(Wk·bq)   (row-constant terms cancel)
        matvec_wb_k<<<1024, 256, 0, stream>>>(wk + l * TSZ, bq + l * HD, wkbq);
        matvec_v_k <<<NB * SEQ, 256, 0, stream>>>(ybh, ybl, wkbq, vbias);
        // MT = Wk·Wq^T  (K-split x8 -> f32 partials -> split bf16)
        gemm3_nt<0, false, 3><<<dim3(8, 8, 8), 256, 0, stream>>>(
            S1h, S1l, S0h, S0l, nullptr, wtmp8, nullptr,
            512, HD, 1024, 512, 512, (long)1 << 20);
        reduce8s_k<<<1024, 256, 0, stream>>>(wtmp8, MTh, MTl);
        // z = y·MT^T
        gemm3_nt<4, false, 3><<<dim3(64, 8, 1), 256, 0, stream>>>(
            ybh, ybl, MTh, MTl, nullptr, zh, zl, DM, DM, DM, 0, 0, 0);
        // scores = z·y^T  (per batch)
        gemm3_nt<0, false, 3><<<dim3(16, 16, NB), 256, 0, stream>>>(
            zh, zl, ybh, ybl, nullptr, scf, nullptr,
            DM, DM, SEQ, (long)SD, (long)SD, (long)SEQ * SEQ);
        softmax_k<<<NB * SEQ, 256, 0, stream>>>(scf, vbias, pbh, pbl);

        // ================= value path: W_vo = Wv·Wo =================
        copy_split_k<<<4096, 256, 0, stream>>>(wv + l * TSZ, S0h, S0l);
        transpose_k <<<dim3(16, 64), 256, 0, stream>>>(wo + l * TSZ, S1h, S1l, HD, DM);
        // c_vo = bv·Wo + bo  (via woT split)
        matvec_bt_k<<<1024, 256, 0, stream>>>(S1h, S1l, bv + l * HD, bo + l * DM, c_vo);
        if (l == 0)
            gemm3_nt<0, false, 3><<<dim3(8, 8, 8), 256, 0, stream>>>(
                S0h, S0l, S1h, S1l, nullptr, wtmp8, nullptr,
                512, HD, 1024, 512, 512, (long)1 << 20);
        else
            gemm3_nt<0, false, 1><<<dim3(8, 8, 8), 256, 0, stream>>>(
                S0h, nullptr, S1h, nullptr, nullptr, wtmp8, nullptr,
                512, HD, 1024, 512, 512, (long)1 << 20);
        reduce8f_k<<<1024, 256, 0, stream>>>(wtmp8, wtmpR);
        transpose_k<<<dim3(16, 16), 256, 0, stream>>>(wtmpR, VOh, VOl, 1024, 1024);
        // u^T = (y·W_vo)^T per batch  [4][1024][2048]
        if (l == 0)
            gemm3_nt<5, false, 3><<<dim3(16, 8, NB), 256, 0, stream>>>(
                ybh, ybl, VOh, VOl, nullptr, uTh, uTl,
                DM, DM, SEQ, (long)SD, 0, (long)DM * SEQ);
        else
            gemm3_nt<5, false, 1><<<dim3(16, 8, NB), 256, 0, stream>>>(
                ybh, nullptr, VOh, nullptr, nullptr, uTh, uTl,
                DM, DM, SEQ, (long)SD, 0, (long)DM * SEQ);
        // attout = P·u + c_vo  -> f32 [8192][1024]
        if (l == 0)
            gemm3_nt<0, true, 3><<<dim3(16, 8, NB), 256, 0, stream>>>(
                pbh, pbl, uTh, uTl, c_vo, attout, nullptr,
                SEQ, SEQ, DM, (long)SEQ * SEQ, (long)DM * SEQ, (long)SEQ * DM);
        else
            gemm3_nt<0, true, 1><<<dim3(16, 8, NB), 256, 0, stream>>>(
                pbh, nullptr, uTh, nullptr, c_vo, attout, nullptr,
                SEQ, SEQ, DM, (long)SEQ * SEQ, (long)DM * SEQ, (long)SEQ * DM);
        // LN1(y + attout)
        ln_stats_k<<<dim3(64, NB), 256, 0, stream>>>(ybh, ybl, attout, part);
        ln_fin_k  <<<NB, 64, 0, stream>>>(part, stats);
        ln_apply_k<<<8192, 256, 0, stream>>>(ybh, ybl, attout,
                                             ln1w + (long)l * SD, ln1b + (long)l * SD,
                                             stats, ybh, ybl, nullptr);

        // ================= FFN path: W_12 = W1·W2 (exact: gelu is AFTER linear2) ===
        copy_split_k<<<4096, 256, 0, stream>>>(w1 + l * TSZ, S0h, S0l);
        transpose_k <<<dim3(16, 64), 256, 0, stream>>>(w2 + l * TSZ, S1h, S1l, HD, DM);
        // c_12 = b1·W2 + b2
        matvec_bt_k<<<1024, 256, 0, stream>>>(S1h, S1l, b1 + l * HD, b2 + l * DM, c_12);
        if (l == 0)
            gemm3_nt<0, false, 3><<<dim3(8, 8, 8), 256, 0, stream>>>(
                S0h, S0l, S1h, S1l, nullptr, wtmp8, nullptr,
                512, HD, 1024, 512, 512, (long)1 << 20);
        else
            gemm3_nt<0, false, 1><<<dim3(8, 8, 8), 256, 0, stream>>>(
                S0h, nullptr, S1h, nullptr, nullptr, wtmp8, nullptr,
                512, HD, 1024, 512, 512, (long)1 << 20);
        reduce8f_k<<<1024, 256, 0, stream>>>(wtmp8, wtmpR);
        transpose_k<<<dim3(16, 16), 256, 0, stream>>>(wtmpR, W12h, W12l, 1024, 1024);
        // ffn = gelu(y·W_12 + c_12) -> f32 [8192][1024]
        if (l == 0)
            gemm3_nt<1, true, 3><<<dim3(64, 8, 1), 256, 0, stream>>>(
                ybh, ybl, W12h, W12l, c_12, ffnf, nullptr, DM, DM, DM, 0, 0, 0);
        else
            gemm3_nt<1, true, 1><<<dim3(64, 8, 1), 256, 0, stream>>>(
                ybh, nullptr, W12h, nullptr, c_12, ffnf, nullptr, DM, DM, DM, 0, 0, 0);
        // LN2(y + ffn); final layer also writes f32 to d_out
        float* fdst = (l == 1) ? (float*)d_out : nullptr;
        ln_stats_k<<<dim3(64, NB), 256, 0, stream>>>(ybh, ybl, ffnf, part);
        ln_fin_k  <<<NB, 64, 0, stream>>>(part, stats);
        ln_apply_k<<<8192, 256, 0, stream>>>(ybh, ybl, ffnf,
                                             ln2w + (long)l * SD, ln2b + (long)l * SD,
                                             stats, ybh, ybl, fdst);
    }
}

// Round 13
// 1185.217 us; speedup vs baseline: 4.0261x; 1.0263x over previous
//
#include <hip/hip_runtime.h>
#include <cstdint>
#include <cstddef>

using bf16 = __bf16;
typedef float f32x4 __attribute__((ext_vector_type(4)));
typedef bf16 bf16x8 __attribute__((ext_vector_type(8)));
typedef bf16 bf16x4 __attribute__((ext_vector_type(4)));

#define NB 4           // batch
#define SEQ 2048
#define DM 1024        // d_model
#define HD 4096        // hidden
#define SD (SEQ*DM)    // 2^21 elems per sample

__device__ __forceinline__ float geluf(float v) {
    return 0.5f * v * (1.0f + erff(v * 0.70710678118654752f));
}

#define GLL(gp, lp) __builtin_amdgcn_global_load_lds( \
    (const __attribute__((address_space(1))) void*)(gp), \
    (__attribute__((address_space(3))) void*)(lp), 16, 0, 0)

// ---------------------------------------------------------------------------
// Split-precision NT GEMM, fused NP-pass, single-buffered (R8/R10/R11 proven
// structure) + 4x4-supertile/XCD-chunk block swizzle (T1-class, bijective):
//   NP=3: C = Ah*Bh + Al*Bh + Ah*Bl  (~17-bit mantissa, f32 accum)
//   NP=1: C = Ah*Bh                  (plain bf16; 32KB LDS -> 4 blocks/CU)
// A: M x K row-major bf16 (pair), Bt: N x K row-major bf16 (pair).
// ldab = row stride of A and B (== K except for K-split launches).
// Tile 128x128x64, 4 waves, 16x16x32 bf16 MFMA, global_load_lds staging,
// chunk XOR swizzle (c' = c ^ (m&7)) on BOTH global source and ds_read addr.
// EPI: 0 = f32 store, 1 = f32 gelu store,
//      4 = split bf16 (hi+lo) store, 5 = split bf16 transposed store
// ---------------------------------------------------------------------------
template<int EPI, bool BIAS, int NP>
__global__ __launch_bounds__(256, NP == 1 ? 4 : 2) void gemm3_nt(
    const bf16* __restrict__ Ah, const bf16* __restrict__ Al,
    const bf16* __restrict__ Bh, const bf16* __restrict__ Bl,
    const float* __restrict__ bias, void* __restrict__ Cg, void* __restrict__ Cl,
    const int K, const int ldab, const int ldc,
    const long sA, const long sB, const long sC)
{
    constexpr int TILE = 128 * 64;                 // elems per plane
    constexpr int LOSZ = (NP == 3) ? TILE : 8;     // lo planes only for NP=3
    __shared__ __align__(16) bf16 smAh[TILE];
    __shared__ __align__(16) bf16 smBh[TILE];
    __shared__ __align__(16) bf16 smAl[LOSZ];
    __shared__ __align__(16) bf16 smBl[LOSZ];

    const int tid  = threadIdx.x;
    const int lane = tid & 63;
    const int wave = tid >> 6;
    const int wr   = (wave >> 1) << 6;
    const int wc   = (wave & 1) << 6;
    const int l15  = lane & 15;
    const int q4   = lane >> 4;

    // ---- block swizzle: XCD chunk + 4x4 output supertile (bijective) ----
    // HW round-robins linear block id over XCDs; chunk transform gives each
    // XCD a contiguous logical range, then supertile-decode gives 4x4 output
    // locality (A- and B-tiles each reused 4x within a small window).
    int bx = blockIdx.x, by = blockIdx.y;
    {
        const int gx = gridDim.x, gy = gridDim.y;
        if (((gx & 3) | (gy & 3)) == 0) {
            const int tot = gx * gy;               // multiple of 16
            const int n   = bx + gx * by;
            const int l   = (n & 7) * (tot >> 3) + (n >> 3);   // XCD chunk
            const int st  = l >> 4, pos = l & 15;              // supertile
            bx = (st % (gx >> 2)) * 4 + (pos & 3);
            by = (st / (gx >> 2)) * 4 + (pos >> 2);
        }
    }

    const long aoff = (long)blockIdx.z * sA + (long)bx * 128 * ldab;
    const long boff = (long)blockIdx.z * sB + (long)by * 128 * ldab;
    const bf16* pAh = Ah + aoff;
    const bf16* pAl = (NP == 3) ? Al + aoff : nullptr;
    const bf16* pBh = Bh + boff;
    const bf16* pBl = (NP == 3) ? Bl + boff : nullptr;

    // staging: chunk = it*256 + tid; row m = chunk>>3;
    // global chunk col = (chunk&7) ^ (m&7)  (pre-swizzled source)
    int srow[4], scol[4];
#pragma unroll
    for (int it = 0; it < 4; ++it) {
        int chunk = it * 256 + tid;
        int m = chunk >> 3;
        srow[it] = m;
        scol[it] = ((chunk & 7) ^ (m & 7)) * 8;
    }

    f32x4 acc[4][4] = {};

    for (int k0 = 0; k0 < K; k0 += 64) {
#pragma unroll
        for (int it = 0; it < 4; ++it) {
            const long go = (long)srow[it] * ldab + (k0 + scol[it]);
            const size_t lo = (size_t)(it * 256 + (wave << 6)) * 8;   // linear fill
            GLL(pAh + go, smAh + lo);
            if constexpr (NP == 3) GLL(pAl + go, smAl + lo);
            GLL(pBh + go, smBh + lo);
            if constexpr (NP == 3) GLL(pBl + go, smBl + lo);
        }
        __syncthreads();   // compiler drains vmcnt(0) before barrier

#pragma unroll
        for (int kk = 0; kk < 2; ++kk) {
            bf16x8 avh[4], avl[4], bvh[4], bvl[4];
#pragma unroll
            for (int i = 0; i < 4; ++i) {
                const int rowa = wr + i * 16 + l15;
                const int ca = ((kk * 4 + q4) ^ (rowa & 7)) * 8;   // swizzled read
                avh[i] = *(const bf16x8*)(smAh + rowa * 64 + ca);
                if constexpr (NP == 3) avl[i] = *(const bf16x8*)(smAl + rowa * 64 + ca);
                const int rowb = wc + i * 16 + l15;
                const int cb = ((kk * 4 + q4) ^ (rowb & 7)) * 8;
                bvh[i] = *(const bf16x8*)(smBh + rowb * 64 + cb);
                if constexpr (NP == 3) bvl[i] = *(const bf16x8*)(smBl + rowb * 64 + cb);
            }
#pragma unroll
            for (int i = 0; i < 4; ++i)
#pragma unroll
                for (int j = 0; j < 4; ++j) {
                    acc[i][j] = __builtin_amdgcn_mfma_f32_16x16x32_bf16(
                        avh[i], bvh[j], acc[i][j], 0, 0, 0);
                    if constexpr (NP == 3) {
                        acc[i][j] = __builtin_amdgcn_mfma_f32_16x16x32_bf16(
                            avl[i], bvh[j], acc[i][j], 0, 0, 0);
                        acc[i][j] = __builtin_amdgcn_mfma_f32_16x16x32_bf16(
                            avh[i], bvl[j], acc[i][j], 0, 0, 0);
                    }
                }
        }
        __syncthreads();
    }

    // epilogue: D col = lane&15, row = (lane>>4)*4 + e
    const long zC = (long)blockIdx.z * sC;
    const int gcol0 = by * 128 + wc + l15;
    const int grow0 = bx * 128 + wr + q4 * 4;
#pragma unroll
    for (int j = 0; j < 4; ++j) {
        const int col = gcol0 + j * 16;
        const float bvz = BIAS ? bias[col] : 0.0f;
#pragma unroll
        for (int i = 0; i < 4; ++i) {
            const int row = grow0 + i * 16;
            if (EPI == 5) {
                bf16x4 oh, ol;
#pragma unroll
                for (int e = 0; e < 4; ++e) {
                    const float v = acc[i][j][e] + bvz;
                    const bf16 hi = (bf16)v;
                    oh[e] = hi;
                    ol[e] = (bf16)(v - (float)hi);
                }
                *(bf16x4*)((bf16*)Cg + zC + (long)col * ldc + row) = oh;
                *(bf16x4*)((bf16*)Cl + zC + (long)col * ldc + row) = ol;
            } else {
#pragma unroll
                for (int e = 0; e < 4; ++e) {
                    float v = acc[i][j][e] + bvz;
                    if (EPI == 1) v = geluf(v);
                    const long off = zC + (long)(row + e) * ldc + col;
                    if (EPI == 4) {
                        const bf16 hi = (bf16)v;
                        ((bf16*)Cg)[off] = hi;
                        ((bf16*)Cl)[off] = (bf16)(v - (float)hi);
                    } else {
                        ((float*)Cg)[off] = v;
                    }
                }
            }
        }
    }
}

// ---------------------------------------------------------------------------
// y = emb[x] (f32) + sinusoidal pos -> split bf16 (hi, lo) residual
// ---------------------------------------------------------------------------
__global__ __launch_bounds__(256) void embed_k(
    const int* __restrict__ x, const float* __restrict__ emb,
    bf16* __restrict__ yh, bf16* __restrict__ yl)
{
    const int bs = blockIdx.x;          // B*S
    const int s = bs & (SEQ - 1);
    const long e0 = (long)x[bs] * DM;
    const int d = threadIdx.x * 4;
    const float4 ev = *(const float4*)(emb + e0 + d);
    float o[4];
    const float fs = (float)s;
#pragma unroll
    for (int e = 0; e < 4; ++e) {
        const int dd = d + e;
        const float div = powf(10000.0f, (float)dd * (1.0f / 1024.0f));
        const float ang = fs / div;
        const float p = (dd & 1) ? cosf(ang) : sinf(ang);
        o[e] = ((const float*)&ev)[e] + p;
    }
    bf16x4 oh, ol;
#pragma unroll
    for (int e = 0; e < 4; ++e) {
        oh[e] = (bf16)o[e];
        ol[e] = (bf16)(o[e] - (float)oh[e]);
    }
    *(bf16x4*)(yh + (long)bs * DM + d) = oh;
    *(bf16x4*)(yl + (long)bs * DM + d) = ol;
}

// ---------------------------------------------------------------------------
// f32 -> split bf16 straight copy (weights used K-contiguous as-is)
// ---------------------------------------------------------------------------
__global__ __launch_bounds__(256) void copy_split_k(
    const float* __restrict__ src, bf16* __restrict__ dh, bf16* __restrict__ dl)
{
    const long i = ((long)blockIdx.x * 256 + threadIdx.x) * 4;
    const float4 v = *(const float4*)(src + i);
    const float vv[4] = {v.x, v.y, v.z, v.w};
    bf16x4 oh, ol;
#pragma unroll
    for (int e = 0; e < 4; ++e) {
        const bf16 hi = (bf16)vv[e];
        oh[e] = hi;
        ol[e] = (bf16)(vv[e] - (float)hi);
    }
    *(bf16x4*)(dh + i) = oh;
    *(bf16x4*)(dl + i) = ol;
}

// ---------------------------------------------------------------------------
// 8-plane f32 partial reduce -> split bf16 (straight, for MT)
// ---------------------------------------------------------------------------
__global__ __launch_bounds__(256) void reduce8s_k(
    const float* __restrict__ p, bf16* __restrict__ dh, bf16* __restrict__ dl)
{
    const long i = ((long)blockIdx.x * 256 + threadIdx.x) * 4;
    const long PL = (long)1 << 20;
    float vv[4] = {0.f, 0.f, 0.f, 0.f};
#pragma unroll
    for (int q = 0; q < 8; ++q) {
        const float4 a = *(const float4*)(p + q * PL + i);
        vv[0] += a.x; vv[1] += a.y; vv[2] += a.z; vv[3] += a.w;
    }
    bf16x4 oh, ol;
#pragma unroll
    for (int e = 0; e < 4; ++e) {
        const bf16 hi = (bf16)vv[e];
        oh[e] = hi;
        ol[e] = (bf16)(vv[e] - (float)hi);
    }
    *(bf16x4*)(dh + i) = oh;
    *(bf16x4*)(dl + i) = ol;
}

// ---------------------------------------------------------------------------
// 8-plane f32 partial reduce + TRANSPOSE -> split bf16 (for W_vo^T, W_12^T)
// src planes are [1024][1024] f32; dst[c][r] = sum_q src_q[r][c]
// ---------------------------------------------------------------------------
__global__ __launch_bounds__(256) void reduce8t_k(
    const float* __restrict__ p, bf16* __restrict__ dsth, bf16* __restrict__ dstl)
{
    __shared__ bf16 th[64][65];
    __shared__ bf16 tl[64][65];
    const long PL = (long)1 << 20;
    const int c0 = blockIdx.x * 64, r0 = blockIdx.y * 64;
    const int t = threadIdx.x;
    const int tr = t >> 4;
    const int tc = (t & 15) * 4;
#pragma unroll
    for (int pp = 0; pp < 4; ++pp) {
        const int r = tr + pp * 16;
        float vv[4] = {0.f, 0.f, 0.f, 0.f};
#pragma unroll
        for (int q = 0; q < 8; ++q) {
            const float4 v = *(const float4*)(p + q * PL + (long)(r0 + r) * 1024 + c0 + tc);
            vv[0] += v.x; vv[1] += v.y; vv[2] += v.z; vv[3] += v.w;
        }
#pragma unroll
        for (int e = 0; e < 4; ++e) {
            const bf16 hi = (bf16)vv[e];
            th[r][tc + e] = hi;
            tl[r][tc + e] = (bf16)(vv[e] - (float)hi);
        }
    }
    __syncthreads();
#pragma unroll
    for (int pp = 0; pp < 4; ++pp) {
        const int c = tr + pp * 16;
        bf16x4 oh, ol;
#pragma unroll
        for (int e = 0; e < 4; ++e) { oh[e] = th[tc + e][c]; ol[e] = tl[tc + e][c]; }
        *(bf16x4*)(dsth + (long)(c0 + c) * 1024 + r0 + tc) = oh;
        *(bf16x4*)(dstl + (long)(c0 + c) * 1024 + r0 + tc) = ol;
    }
}

// ---------------------------------------------------------------------------
// f32 -> split bf16 transpose: src R x C (f32) -> dst C x R (hi, lo)
// ---------------------------------------------------------------------------
__global__ __launch_bounds__(256) void transpose_k(
    const float* __restrict__ src, bf16* __restrict__ dsth, bf16* __restrict__ dstl,
    int R, int C)
{
    __shared__ bf16 th[64][65];
    __shared__ bf16 tl[64][65];
    const int c0 = blockIdx.x * 64, r0 = blockIdx.y * 64;
    const int t = threadIdx.x;
    const int tr = t >> 4;
    const int tc = (t & 15) * 4;
#pragma unroll
    for (int p = 0; p < 4; ++p) {
        const int r = tr + p * 16;
        const float4 v = *(const float4*)(src + (long)(r0 + r) * C + c0 + tc);
        const float vv[4] = {v.x, v.y, v.z, v.w};
#pragma unroll
        for (int e = 0; e < 4; ++e) {
            const bf16 hi = (bf16)vv[e];
            th[r][tc + e] = hi;
            tl[r][tc + e] = (bf16)(vv[e] - (float)hi);
        }
    }
    __syncthreads();
#pragma unroll
    for (int p = 0; p < 4; ++p) {
        const int c = tr + p * 16;
        bf16x4 oh, ol;
#pragma unroll
        for (int e = 0; e < 4; ++e) { oh[e] = th[tc + e][c]; ol[e] = tl[tc + e][c]; }
        *(bf16x4*)(dsth + (long)(c0 + c) * R + r0 + tc) = oh;
        *(bf16x4*)(dstl + (long)(c0 + c) * R + r0 + tc) = ol;
    }
}

// ---------------------------------------------------------------------------
// wb[d] = sum_h W[d][h] * b[h]   (f32, W is [1024][4096])
// ---------------------------------------------------------------------------
__global__ __launch_bounds__(256) void matvec_wb_k(
    const float* __restrict__ W, const float* __restrict__ b, float* __restrict__ out)
{
    const int d = blockIdx.x;
    const int t = threadIdx.x;
    float s = 0.f;
    for (int h = t * 4; h < HD; h += 1024) {
        const float4 wv = *(const float4*)(W + (long)d * HD + h);
        const float4 bv = *(const float4*)(b + h);
        s += wv.x * bv.x + wv.y * bv.y + wv.z * bv.z + wv.w * bv.w;
    }
#pragma unroll
    for (int o = 32; o; o >>= 1) s += __shfl_xor(s, o);
    __shared__ float red[4];
    if ((t & 63) == 0) red[t >> 6] = s;
    __syncthreads();
    if (t == 0) out[d] = red[0] + red[1] + red[2] + red[3];
}

// ---------------------------------------------------------------------------
// out[j] = sum_h (BtH+BtL)[j][h] * b[h] + add[j]   (Bt split [1024][4096])
// ---------------------------------------------------------------------------
__global__ __launch_bounds__(256) void matvec_bt_k(
    const bf16* __restrict__ bth, const bf16* __restrict__ btl,
    const float* __restrict__ b, const float* __restrict__ add,
    float* __restrict__ out)
{
    const int j = blockIdx.x;
    const int t = threadIdx.x;
    float s = 0.f;
    for (int h = t * 4; h < HD; h += 1024) {
        const bf16x4 hx = *(const bf16x4*)(bth + (long)j * HD + h);
        const bf16x4 lx = *(const bf16x4*)(btl + (long)j * HD + h);
        const float4 bv = *(const float4*)(b + h);
        s += ((float)hx[0] + (float)lx[0]) * bv.x + ((float)hx[1] + (float)lx[1]) * bv.y
           + ((float)hx[2] + (float)lx[2]) * bv.z + ((float)hx[3] + (float)lx[3]) * bv.w;
    }
#pragma unroll
    for (int o = 32; o; o >>= 1) s += __shfl_xor(s, o);
    __shared__ float red[4];
    if ((t & 63) == 0) red[t >> 6] = s;
    __syncthreads();
    if (t == 0) out[j] = red[0] + red[1] + red[2] + red[3] + add[j];
}

// ---------------------------------------------------------------------------
// v[r] = sum_d (yh+yl)[r][d] * w[d]   (key-side bias term for softmax)
// ---------------------------------------------------------------------------
__global__ __launch_bounds__(256) void matvec_v_k(
    const bf16* __restrict__ yh, const bf16* __restrict__ yl,
    const float* __restrict__ w, float* __restrict__ v)
{
    const long r = blockIdx.x;
    const int t = threadIdx.x;
    const bf16x4 h = *(const bf16x4*)(yh + r * DM + t * 4);
    const bf16x4 l = *(const bf16x4*)(yl + r * DM + t * 4);
    const float4 wv = *(const float4*)(w + t * 4);
    float s = ((float)h[0] + (float)l[0]) * wv.x + ((float)h[1] + (float)l[1]) * wv.y
            + ((float)h[2] + (float)l[2]) * wv.z + ((float)h[3] + (float)l[3]) * wv.w;
#pragma unroll
    for (int o = 32; o; o >>= 1) s += __shfl_xor(s, o);
    __shared__ float red[4];
    if ((t & 63) == 0) red[t >> 6] = s;
    __syncthreads();
    if (t == 0) v[r] = red[0] + red[1] + red[2] + red[3];
}

// ---------------------------------------------------------------------------
// Row softmax with key-side column bias: P = softmax(S[i][:] + v[:])
// 2048 f32 per row -> split bf16 (hi, lo)
// ---------------------------------------------------------------------------
__global__ __launch_bounds__(256) void softmax_k(
    const float* __restrict__ S, const float* __restrict__ v,
    bf16* __restrict__ Ph, bf16* __restrict__ Pl)
{
    const long row = blockIdx.x;
    const float4* src = (const float4*)(S + (row << 11));
    const float* vr = v + (long)(row >> 11) * SEQ;
    const int t = threadIdx.x;
    float4 a = src[t], b = src[256 + t];
    const float4 va = *(const float4*)(vr + t * 4);
    const float4 vb = *(const float4*)(vr + 1024 + t * 4);
    a.x += va.x; a.y += va.y; a.z += va.z; a.w += va.w;
    b.x += vb.x; b.y += vb.y; b.z += vb.z; b.w += vb.w;
    float m = fmaxf(fmaxf(fmaxf(a.x, a.y), fmaxf(a.z, a.w)),
                    fmaxf(fmaxf(b.x, b.y), fmaxf(b.z, b.w)));
#pragma unroll
    for (int o = 32; o; o >>= 1) m = fmaxf(m, __shfl_xor(m, o));
    __shared__ float red1[4], red2[4];
    const int wv = t >> 6;
    if ((t & 63) == 0) red1[wv] = m;
    __syncthreads();
    m = fmaxf(fmaxf(red1[0], red1[1]), fmaxf(red1[2], red1[3]));

    a.x = expf(a.x - m); a.y = expf(a.y - m); a.z = expf(a.z - m); a.w = expf(a.w - m);
    b.x = expf(b.x - m); b.y = expf(b.y - m); b.z = expf(b.z - m); b.w = expf(b.w - m);
    float s = a.x + a.y + a.z + a.w + b.x + b.y + b.z + b.w;
#pragma unroll
    for (int o = 32; o; o >>= 1) s += __shfl_xor(s, o);
    if ((t & 63) == 0) red2[wv] = s;
    __syncthreads();
    s = red2[0] + red2[1] + red2[2] + red2[3];
    const float inv = 1.0f / s;

    const float pv[8] = {a.x * inv, a.y * inv, a.z * inv, a.w * inv,
                         b.x * inv, b.y * inv, b.z * inv, b.w * inv};
    bf16x4 h0, l0, h1, l1;
#pragma unroll
    for (int e = 0; e < 4; ++e) {
        const bf16 hi = (bf16)pv[e];
        h0[e] = hi; l0[e] = (bf16)(pv[e] - (float)hi);
        const bf16 hj = (bf16)pv[4 + e];
        h1[e] = hj; l1[e] = (bf16)(pv[4 + e] - (float)hj);
    }
    *(bf16x4*)(Ph + (row << 11) + t * 4) = h0;
    *(bf16x4*)(Pl + (row << 11) + t * 4) = l0;
    *(bf16x4*)(Ph + (row << 11) + 1024 + t * 4) = h1;
    *(bf16x4*)(Pl + (row << 11) + 1024 + t * 4) = l1;
}

// ---------------------------------------------------------------------------
// LayerNorm over whole (S,D) sample; residual carried as split bf16 (hi+lo).
// ---------------------------------------------------------------------------
__global__ __launch_bounds__(256) void ln_stats_k(
    const bf16* __restrict__ yh, const bf16* __restrict__ yl,
    const float* __restrict__ r, float2* __restrict__ part)
{
    const int b = blockIdx.y;
    const long base = (long)b * SD + (long)blockIdx.x * (SD / 64);
    float s = 0.f, q = 0.f;
    for (int i = threadIdx.x; i < (SD / 64) / 4; i += 256) {
        const bf16x4 h = *(const bf16x4*)(yh + base + i * 4);
        const bf16x4 l = *(const bf16x4*)(yl + base + i * 4);
        const float4 c = *(const float4*)(r + base + i * 4);
        const float cc[4] = {c.x, c.y, c.z, c.w};
#pragma unroll
        for (int e = 0; e < 4; ++e) {
            const float x = (float)h[e] + (float)l[e] + cc[e];
            s += x; q += x * x;
        }
    }
#pragma unroll
    for (int o = 32; o; o >>= 1) { s += __shfl_xor(s, o); q += __shfl_xor(q, o); }
    __shared__ float rs[4], rq[4];
    const int wv = threadIdx.x >> 6;
    if ((threadIdx.x & 63) == 0) { rs[wv] = s; rq[wv] = q; }
    __syncthreads();
    if (threadIdx.x == 0)
        part[b * 64 + blockIdx.x] = make_float2(rs[0] + rs[1] + rs[2] + rs[3],
                                                rq[0] + rq[1] + rq[2] + rq[3]);
}

__global__ void ln_fin_k(const float2* __restrict__ part, float2* __restrict__ stats)
{
    const int b = blockIdx.x;
    const float2 p = part[b * 64 + threadIdx.x];
    float s = p.x, q = p.y;
#pragma unroll
    for (int o = 32; o; o >>= 1) { s += __shfl_xor(s, o); q += __shfl_xor(q, o); }
    if (threadIdx.x == 0) {
        const float inv_n = 1.0f / (float)SD;
        const float mean = s * inv_n;
        const float var = fmaxf(q * inv_n - mean * mean, 0.f);
        stats[b] = make_float2(mean, rsqrtf(var + 1e-5f));
    }
}

__global__ __launch_bounds__(256) void ln_apply_k(
    const bf16* __restrict__ yh_in, const bf16* __restrict__ yl_in,
    const float* __restrict__ r,
    const float* __restrict__ w, const float* __restrict__ bb,
    const float2* __restrict__ stats,
    bf16* __restrict__ yh_out, bf16* __restrict__ yl_out, float* __restrict__ fout)
{
    const long i = ((long)blockIdx.x * 256 + threadIdx.x) * 4;
    const int smp = (int)(i >> 21);
    const long sd = i & (SD - 1);
    const float2 st = stats[smp];
    const bf16x4 h = *(const bf16x4*)(yh_in + i);
    const bf16x4 l = *(const bf16x4*)(yl_in + i);
    const float4 c = *(const float4*)(r + i);
    const float4 wv = *(const float4*)(w + sd);
    const float4 bv = *(const float4*)(bb + sd);
    const float cc[4] = {c.x, c.y, c.z, c.w};
    const float ww[4] = {wv.x, wv.y, wv.z, wv.w};
    const float bbx[4] = {bv.x, bv.y, bv.z, bv.w};
    float o[4];
#pragma unroll
    for (int e = 0; e < 4; ++e) {
        const float x = (float)h[e] + (float)l[e] + cc[e];
        o[e] = (x - st.x) * st.y * ww[e] + bbx[e];
    }
    bf16x4 oh, ol;
#pragma unroll
    for (int e = 0; e < 4; ++e) {
        oh[e] = (bf16)o[e];
        ol[e] = (bf16)(o[e] - (float)oh[e]);
    }
    *(bf16x4*)(yh_out + i) = oh;
    *(bf16x4*)(yl_out + i) = ol;
    if (fout != nullptr) *(float4*)(fout + i) = *(float4*)o;
}

// ---------------------------------------------------------------------------
extern "C" void kernel_launch(void* const* d_in, const int* in_sizes, int n_in,
                              void* d_out, int out_size, void* d_ws, size_t ws_size,
                              hipStream_t stream)
{
    (void)in_sizes; (void)n_in; (void)out_size; (void)ws_size;

    const int*   x    = (const int*)  d_in[0];
    const float* emb  = (const float*)d_in[1];
    const float* wq   = (const float*)d_in[2];
    const float* bq   = (const float*)d_in[3];
    const float* wk   = (const float*)d_in[4];
    const float* bk   = (const float*)d_in[5];
    const float* wv   = (const float*)d_in[6];
    const float* bv   = (const float*)d_in[7];
    const float* wo   = (const float*)d_in[8];
    const float* bo   = (const float*)d_in[9];
    const float* w1   = (const float*)d_in[10];
    const float* b1   = (const float*)d_in[11];
    const float* w2   = (const float*)d_in[12];
    const float* b2   = (const float*)d_in[13];
    const float* ln1w = (const float*)d_in[14];
    const float* ln1b = (const float*)d_in[15];
    const float* ln2w = (const float*)d_in[16];
    const float* ln2b = (const float*)d_in[17];
    (void)bk;   // cancels in softmax (row-constant)

    // Workspace — peak 352 MiB (R2 proved ≥384 MiB usable; R3's 512 faulted).
    char* ws = (char*)d_ws;
    const size_t MB = (size_t)1 << 20;
    bf16*   ybh   = (bf16*) (ws);                  //  16 MiB residual hi
    bf16*   ybl   = (bf16*) (ws + 16  * MB);       //  16 MiB residual lo
    bf16*   S0h   = (bf16*) (ws + 32  * MB);       //   8 MiB weight slot 0 hi
    bf16*   S0l   = (bf16*) (ws + 40  * MB);       //   8 MiB weight slot 0 lo
    bf16*   S1h   = (bf16*) (ws + 48  * MB);       //   8 MiB weight slot 1 hi
    bf16*   S1l   = (bf16*) (ws + 56  * MB);       //   8 MiB weight slot 1 lo
    bf16*   MTh   = (bf16*) (ws + 64  * MB);       //   2 MiB MT hi
    bf16*   MTl   = (bf16*) (ws + 66  * MB);       //   2 MiB MT lo
    bf16*   VOh   = (bf16*) (ws + 68  * MB);       //   2 MiB W_vo^T hi
    bf16*   VOl   = (bf16*) (ws + 70  * MB);       //   2 MiB W_vo^T lo
    bf16*   W12h  = (bf16*) (ws + 72  * MB);       //   2 MiB W_12^T hi
    bf16*   W12l  = (bf16*) (ws + 74  * MB);       //   2 MiB W_12^T lo
    float*  wkbq  = (float*)(ws + 76  * MB);                //  4 KiB
    float*  c_vo  = (float*)(ws + 76  * MB + 0x10000);      //  4 KiB
    float*  c_12  = (float*)(ws + 76  * MB + 0x20000);      //  4 KiB
    float*  vbias = (float*)(ws + 76  * MB + 0x30000);      // 32 KiB
    float2* part  = (float2*)(ws + 76 * MB + 0x40000);
    float2* stats = (float2*)(ws + 76 * MB + 0x50000);
    float*  wtmp8 = (float*)(ws + 80  * MB);       //  32 MiB K-split f32 partials
    bf16*   zh    = (bf16*) (ws + 128 * MB);       //  16 MiB z hi [8192][1024]
    bf16*   zl    = (bf16*) (ws + 144 * MB);       //  16 MiB z lo
    bf16*   uTh   = (bf16*) (ws + 160 * MB);       //  16 MiB u^T hi [4][1024][2048]
    bf16*   uTl   = (bf16*) (ws + 176 * MB);       //  16 MiB u^T lo
    float*  scf   = (float*)(ws + 192 * MB);       //  64 MiB scores f32 [4][2048][2048]
    bf16*   pbh   = (bf16*) (ws + 256 * MB);       //  32 MiB probs hi
    bf16*   pbl   = (bf16*) (ws + 288 * MB);       //  32 MiB probs lo
    float*  attout= (float*)(ws + 320 * MB);       //  32 MiB f32 [8192][1024]
    float*  ffnf  = attout;                        //  (attout dead after LN1)

    const long TSZ = (long)DM * HD;

    embed_k<<<NB * SEQ, 256, 0, stream>>>(x, emb, ybh, ybl);

    for (int l = 0; l < 2; ++l) {
        // ================= score path (always NP=3) =================
        // wq, wk: straight split copies (used K-contiguous as-is)
        copy_split_k<<<4096, 256, 0, stream>>>(wq + l * TSZ, S0h, S0l);
        copy_split_k<<<4096, 256, 0, stream>>>(wk + l * TSZ, S1h, S1l);
        // key-side bias: vbias = y·(Wk·bq)   (row-constant terms cancel)
        matvec_wb_k<<<1024, 256, 0, stream>>>(wk + l * TSZ, bq + l * HD, wkbq);
        matvec_v_k <<<NB * SEQ, 256, 0, stream>>>(ybh, ybl, wkbq, vbias);
        // MT = Wk·Wq^T  (K-split x8 -> f32 partials -> split bf16)
        gemm3_nt<0, false, 3><<<dim3(8, 8, 8), 256, 0, stream>>>(
            S1h, S1l, S0h, S0l, nullptr, wtmp8, nullptr,
            512, HD, 1024, 512, 512, (long)1 << 20);
        reduce8s_k<<<1024, 256, 0, stream>>>(wtmp8, MTh, MTl);
        // z = y·MT^T
        gemm3_nt<4, false, 3><<<dim3(64, 8, 1), 256, 0, stream>>>(
            ybh, ybl, MTh, MTl, nullptr, zh, zl, DM, DM, DM, 0, 0, 0);
        // scores = z·y^T  (per batch)
        gemm3_nt<0, false, 3><<<dim3(16, 16, NB), 256, 0, stream>>>(
            zh, zl, ybh, ybl, nullptr, scf, nullptr,
            DM, DM, SEQ, (long)SD, (long)SD, (long)SEQ * SEQ);
        softmax_k<<<NB * SEQ, 256, 0, stream>>>(scf, vbias, pbh, pbl);

        // ================= value path: W_vo = Wv·Wo =================
        copy_split_k<<<4096, 256, 0, stream>>>(wv + l * TSZ, S0h, S0l);
        transpose_k <<<dim3(16, 64), 256, 0, stream>>>(wo + l * TSZ, S1h, S1l, HD, DM);
        // c_vo = bv·Wo + bo  (via woT split)
        matvec_bt_k<<<1024, 256, 0, stream>>>(S1h, S1l, bv + l * HD, bo + l * DM, c_vo);
        if (l == 0)
            gemm3_nt<0, false, 3><<<dim3(8, 8, 8), 256, 0, stream>>>(
                S0h, S0l, S1h, S1l, nullptr, wtmp8, nullptr,
                512, HD, 1024, 512, 512, (long)1 << 20);
        else
            gemm3_nt<0, false, 1><<<dim3(8, 8, 8), 256, 0, stream>>>(
                S0h, nullptr, S1h, nullptr, nullptr, wtmp8, nullptr,
                512, HD, 1024, 512, 512, (long)1 << 20);
        reduce8t_k<<<dim3(16, 16), 256, 0, stream>>>(wtmp8, VOh, VOl);
        // u^T = (y·W_vo)^T per batch  [4][1024][2048]
        if (l == 0)
            gemm3_nt<5, false, 3><<<dim3(16, 8, NB), 256, 0, stream>>>(
                ybh, ybl, VOh, VOl, nullptr, uTh, uTl,
                DM, DM, SEQ, (long)SD, 0, (long)DM * SEQ);
        else
            gemm3_nt<5, false, 1><<<dim3(16, 8, NB), 256, 0, stream>>>(
                ybh, nullptr, VOh, nullptr, nullptr, uTh, uTl,
                DM, DM, SEQ, (long)SD, 0, (long)DM * SEQ);
        // attout = P·u + c_vo  -> f32 [8192][1024]
        if (l == 0)
            gemm3_nt<0, true, 3><<<dim3(16, 8, NB), 256, 0, stream>>>(
                pbh, pbl, uTh, uTl, c_vo, attout, nullptr,
                SEQ, SEQ, DM, (long)SEQ * SEQ, (long)DM * SEQ, (long)SEQ * DM);
        else
            gemm3_nt<0, true, 1><<<dim3(16, 8, NB), 256, 0, stream>>>(
                pbh, nullptr, uTh, nullptr, c_vo, attout, nullptr,
                SEQ, SEQ, DM, (long)SEQ * SEQ, (long)DM * SEQ, (long)SEQ * DM);
        // LN1(y + attout)
        ln_stats_k<<<dim3(64, NB), 256, 0, stream>>>(ybh, ybl, attout, part);
        ln_fin_k  <<<NB, 64, 0, stream>>>(part, stats);
        ln_apply_k<<<8192, 256, 0, stream>>>(ybh, ybl, attout,
                                             ln1w + (long)l * SD, ln1b + (long)l * SD,
                                             stats, ybh, ybl, nullptr);

        // ================= FFN path: W_12 = W1·W2 (exact: gelu is AFTER linear2) ===
        copy_split_k<<<4096, 256, 0, stream>>>(w1 + l * TSZ, S0h, S0l);
        transpose_k <<<dim3(16, 64), 256, 0, stream>>>(w2 + l * TSZ, S1h, S1l, HD, DM);
        // c_12 = b1·W2 + b2
        matvec_bt_k<<<1024, 256, 0, stream>>>(S1h, S1l, b1 + l * HD, b2 + l * DM, c_12);
        if (l == 0)
            gemm3_nt<0, false, 3><<<dim3(8, 8, 8), 256, 0, stream>>>(
                S0h, S0l, S1h, S1l, nullptr, wtmp8, nullptr,
                512, HD, 1024, 512, 512, (long)1 << 20);
        else
            gemm3_nt<0, false, 1><<<dim3(8, 8, 8), 256, 0, stream>>>(
                S0h, nullptr, S1h, nullptr, nullptr, wtmp8, nullptr,
                512, HD, 1024, 512, 512, (long)1 << 20);
        reduce8t_k<<<dim3(16, 16), 256, 0, stream>>>(wtmp8, W12h, W12l);
        // ffn = gelu(y·W_12 + c_12) -> f32 [8192][1024]
        if (l == 0)
            gemm3_nt<1, true, 3><<<dim3(64, 8, 1), 256, 0, stream>>>(
                ybh, ybl, W12h, W12l, c_12, ffnf, nullptr, DM, DM, DM, 0, 0, 0);
        else
            gemm3_nt<1, true, 1><<<dim3(64, 8, 1), 256, 0, stream>>>(
                ybh, nullptr, W12h, nullptr, c_12, ffnf, nullptr, DM, DM, DM, 0, 0, 0);
        // LN2(y + ffn); final layer also writes f32 to d_out
        float* fdst = (l == 1) ? (float*)d_out : nullptr;
        ln_stats_k<<<dim3(64, NB), 256, 0, stream>>>(ybh, ybl, ffnf, part);
        ln_fin_k  <<<NB, 64, 0, stream>>>(part, stats);
        ln_apply_k<<<8192, 256, 0, stream>>>(ybh, ybl, ffnf,
                                             ln2w + (long)l * SD, ln2b + (long)l * SD,
                                             stats, ybh, ybl, fdst);
    }
}

// Round 14
// 1015.566 us; speedup vs baseline: 4.6986x; 1.1671x over previous
//
#include <hip/hip_runtime.h>
#include <cstdint>
#include <cstddef>

using bf16 = __bf16;
using f16  = _Float16;
typedef float f32x4 __attribute__((ext_vector_type(4)));
typedef bf16 bf16x8 __attribute__((ext_vector_type(8)));
typedef bf16 bf16x4 __attribute__((ext_vector_type(4)));
typedef f16  f16x8  __attribute__((ext_vector_type(8)));
typedef f16  f16x4  __attribute__((ext_vector_type(4)));

#define NB 4           // batch
#define SEQ 2048
#define DM 1024        // d_model
#define HD 4096        // hidden
#define SD (SEQ*DM)    // 2^21 elems per sample

__device__ __forceinline__ float geluf(float v) {
    return 0.5f * v * (1.0f + erff(v * 0.70710678118654752f));
}

#define GLL(gp, lp) __builtin_amdgcn_global_load_lds( \
    (const __attribute__((address_space(1))) void*)(gp), \
    (__attribute__((address_space(3))) void*)(lp), 16, 0, 0)

// ---------------------------------------------------------------------------
// Precision-tiered NT GEMM (R10 proven single-buffer structure + R13 swizzle):
//   NP=3 (DT=0): C = Ah*Bh + Al*Bh + Ah*Bl  (split bf16, ~17-bit mantissa)
//   NP=1, DT=0 : C = Ah*Bh                  (plain bf16)
//   NP=1, DT=1 : C = A*B with fp16 operands (10-bit mantissa, 1 pass)
// A: M x K row-major (pair), Bt: N x K row-major (pair); 2-byte elements.
// ldab = row stride of A and B. Tile 128x128x64, 4 waves, 16x16x32 MFMA,
// global_load_lds staging, chunk XOR swizzle both-sides, 4x4-supertile/XCD
// block swizzle.
// EPI: 0 = f32 (+bias), 1 = f32 gelu (+bias), 4 = split bf16 store,
//      5 = split bf16 transposed, 6 = fp16 store, 7 = fp16 transposed store
// ---------------------------------------------------------------------------
template<int EPI, bool BIAS, int NP, int DT>
__global__ __launch_bounds__(256, NP == 1 ? 4 : 2) void gemm3_nt(
    const bf16* __restrict__ Ah, const bf16* __restrict__ Al,
    const bf16* __restrict__ Bh, const bf16* __restrict__ Bl,
    const float* __restrict__ bias, void* __restrict__ Cg, void* __restrict__ Cl,
    const int K, const int ldab, const int ldc,
    const long sA, const long sB, const long sC)
{
    constexpr int TILE = 128 * 64;                 // elems per plane
    constexpr int LOSZ = (NP == 3) ? TILE : 8;     // lo planes only for NP=3
    __shared__ __align__(16) bf16 smAh[TILE];
    __shared__ __align__(16) bf16 smBh[TILE];
    __shared__ __align__(16) bf16 smAl[LOSZ];
    __shared__ __align__(16) bf16 smBl[LOSZ];

    const int tid  = threadIdx.x;
    const int lane = tid & 63;
    const int wave = tid >> 6;
    const int wr   = (wave >> 1) << 6;
    const int wc   = (wave & 1) << 6;
    const int l15  = lane & 15;
    const int q4   = lane >> 4;

    // ---- block swizzle: XCD chunk + 4x4 output supertile (bijective) ----
    int bx = blockIdx.x, by = blockIdx.y;
    {
        const int gx = gridDim.x, gy = gridDim.y;
        if (((gx & 3) | (gy & 3)) == 0) {
            const int tot = gx * gy;               // multiple of 16
            const int n   = bx + gx * by;
            const int l   = (n & 7) * (tot >> 3) + (n >> 3);   // XCD chunk
            const int st  = l >> 4, pos = l & 15;              // supertile
            bx = (st % (gx >> 2)) * 4 + (pos & 3);
            by = (st / (gx >> 2)) * 4 + (pos >> 2);
        }
    }

    const long aoff = (long)blockIdx.z * sA + (long)bx * 128 * ldab;
    const long boff = (long)blockIdx.z * sB + (long)by * 128 * ldab;
    const bf16* pAh = Ah + aoff;
    const bf16* pAl = (NP == 3) ? Al + aoff : nullptr;
    const bf16* pBh = Bh + boff;
    const bf16* pBl = (NP == 3) ? Bl + boff : nullptr;

    int srow[4], scol[4];
#pragma unroll
    for (int it = 0; it < 4; ++it) {
        int chunk = it * 256 + tid;
        int m = chunk >> 3;
        srow[it] = m;
        scol[it] = ((chunk & 7) ^ (m & 7)) * 8;
    }

    f32x4 acc[4][4] = {};

    for (int k0 = 0; k0 < K; k0 += 64) {
#pragma unroll
        for (int it = 0; it < 4; ++it) {
            const long go = (long)srow[it] * ldab + (k0 + scol[it]);
            const size_t lo = (size_t)(it * 256 + (wave << 6)) * 8;   // linear fill
            GLL(pAh + go, smAh + lo);
            if constexpr (NP == 3) GLL(pAl + go, smAl + lo);
            GLL(pBh + go, smBh + lo);
            if constexpr (NP == 3) GLL(pBl + go, smBl + lo);
        }
        __syncthreads();

#pragma unroll
        for (int kk = 0; kk < 2; ++kk) {
            bf16x8 avh[4], avl[4], bvh[4], bvl[4];
#pragma unroll
            for (int i = 0; i < 4; ++i) {
                const int rowa = wr + i * 16 + l15;
                const int ca = ((kk * 4 + q4) ^ (rowa & 7)) * 8;   // swizzled read
                avh[i] = *(const bf16x8*)(smAh + rowa * 64 + ca);
                if constexpr (NP == 3) avl[i] = *(const bf16x8*)(smAl + rowa * 64 + ca);
                const int rowb = wc + i * 16 + l15;
                const int cb = ((kk * 4 + q4) ^ (rowb & 7)) * 8;
                bvh[i] = *(const bf16x8*)(smBh + rowb * 64 + cb);
                if constexpr (NP == 3) bvl[i] = *(const bf16x8*)(smBl + rowb * 64 + cb);
            }
#pragma unroll
            for (int i = 0; i < 4; ++i)
#pragma unroll
                for (int j = 0; j < 4; ++j) {
                    if constexpr (DT == 1) {
                        acc[i][j] = __builtin_amdgcn_mfma_f32_16x16x32_f16(
                            *(const f16x8*)&avh[i], *(const f16x8*)&bvh[j],
                            acc[i][j], 0, 0, 0);
                    } else {
                        acc[i][j] = __builtin_amdgcn_mfma_f32_16x16x32_bf16(
                            avh[i], bvh[j], acc[i][j], 0, 0, 0);
                        if constexpr (NP == 3) {
                            acc[i][j] = __builtin_amdgcn_mfma_f32_16x16x32_bf16(
                                avl[i], bvh[j], acc[i][j], 0, 0, 0);
                            acc[i][j] = __builtin_amdgcn_mfma_f32_16x16x32_bf16(
                                avh[i], bvl[j], acc[i][j], 0, 0, 0);
                        }
                    }
                }
        }
        __syncthreads();
    }

    // epilogue: D col = lane&15, row = (lane>>4)*4 + e
    const long zC = (long)blockIdx.z * sC;
    const int gcol0 = by * 128 + wc + l15;
    const int grow0 = bx * 128 + wr + q4 * 4;
#pragma unroll
    for (int j = 0; j < 4; ++j) {
        const int col = gcol0 + j * 16;
        const float bvz = BIAS ? bias[col] : 0.0f;
#pragma unroll
        for (int i = 0; i < 4; ++i) {
            const int row = grow0 + i * 16;
            if (EPI == 5) {
                bf16x4 oh, ol;
#pragma unroll
                for (int e = 0; e < 4; ++e) {
                    const float v = acc[i][j][e] + bvz;
                    const bf16 hi = (bf16)v;
                    oh[e] = hi;
                    ol[e] = (bf16)(v - (float)hi);
                }
                *(bf16x4*)((bf16*)Cg + zC + (long)col * ldc + row) = oh;
                *(bf16x4*)((bf16*)Cl + zC + (long)col * ldc + row) = ol;
            } else if (EPI == 7) {
                f16x4 o;
#pragma unroll
                for (int e = 0; e < 4; ++e) o[e] = (f16)(acc[i][j][e] + bvz);
                *(f16x4*)((f16*)Cg + zC + (long)col * ldc + row) = o;
            } else {
#pragma unroll
                for (int e = 0; e < 4; ++e) {
                    float v = acc[i][j][e] + bvz;
                    if (EPI == 1) v = geluf(v);
                    const long off = zC + (long)(row + e) * ldc + col;
                    if (EPI == 4) {
                        const bf16 hi = (bf16)v;
                        ((bf16*)Cg)[off] = hi;
                        ((bf16*)Cl)[off] = (bf16)(v - (float)hi);
                    } else if (EPI == 6) {
                        ((f16*)Cg)[off] = (f16)v;
                    } else {
                        ((float*)Cg)[off] = v;
                    }
                }
            }
        }
    }
}

// ---------------------------------------------------------------------------
// y = emb[x] + pos -> split bf16 + fp16 plane; optional vbias row-dot
// ---------------------------------------------------------------------------
__global__ __launch_bounds__(256) void embed_k(
    const int* __restrict__ x, const float* __restrict__ emb,
    bf16* __restrict__ yh, bf16* __restrict__ yl, f16* __restrict__ yf16,
    const float* __restrict__ wkbq, float* __restrict__ vb)
{
    const int bs = blockIdx.x;          // row
    const int s = bs & (SEQ - 1);
    const long e0 = (long)x[bs] * DM;
    const int d = threadIdx.x * 4;
    const float4 ev = *(const float4*)(emb + e0 + d);
    float o[4];
    const float fs = (float)s;
#pragma unroll
    for (int e = 0; e < 4; ++e) {
        const int dd = d + e;
        const float div = powf(10000.0f, (float)dd * (1.0f / 1024.0f));
        const float ang = fs / div;
        const float p = (dd & 1) ? cosf(ang) : sinf(ang);
        o[e] = ((const float*)&ev)[e] + p;
    }
    bf16x4 oh, ol; f16x4 of;
#pragma unroll
    for (int e = 0; e < 4; ++e) {
        oh[e] = (bf16)o[e];
        ol[e] = (bf16)(o[e] - (float)oh[e]);
        of[e] = (f16)o[e];
    }
    *(bf16x4*)(yh + (long)bs * DM + d) = oh;
    *(bf16x4*)(yl + (long)bs * DM + d) = ol;
    *(f16x4*) (yf16 + (long)bs * DM + d) = of;
    // vbias[bs] = dot(o_row, wkbq)
    const float4 wv = *(const float4*)(wkbq + d);
    float sdot = o[0] * wv.x + o[1] * wv.y + o[2] * wv.z + o[3] * wv.w;
#pragma unroll
    for (int off = 32; off; off >>= 1) sdot += __shfl_xor(sdot, off);
    __shared__ float red[4];
    if ((threadIdx.x & 63) == 0) red[threadIdx.x >> 6] = sdot;
    __syncthreads();
    if (threadIdx.x == 0) vb[bs] = red[0] + red[1] + red[2] + red[3];
}

// ---------------------------------------------------------------------------
// f32 -> split bf16 straight copy
// ---------------------------------------------------------------------------
__global__ __launch_bounds__(256) void copy_split_k(
    const float* __restrict__ src, bf16* __restrict__ dh, bf16* __restrict__ dl)
{
    const long i = ((long)blockIdx.x * 256 + threadIdx.x) * 4;
    const float4 v = *(const float4*)(src + i);
    const float vv[4] = {v.x, v.y, v.z, v.w};
    bf16x4 oh, ol;
#pragma unroll
    for (int e = 0; e < 4; ++e) {
        const bf16 hi = (bf16)vv[e];
        oh[e] = hi;
        ol[e] = (bf16)(vv[e] - (float)hi);
    }
    *(bf16x4*)(dh + i) = oh;
    *(bf16x4*)(dl + i) = ol;
}

// ---------------------------------------------------------------------------
// 8-plane f32 reduce -> split bf16 + fp16 (straight, for MT)
// ---------------------------------------------------------------------------
__global__ __launch_bounds__(256) void reduce8s_k(
    const float* __restrict__ p, bf16* __restrict__ dh, bf16* __restrict__ dl,
    f16* __restrict__ df)
{
    const long i = ((long)blockIdx.x * 256 + threadIdx.x) * 4;
    const long PL = (long)1 << 20;
    float vv[4] = {0.f, 0.f, 0.f, 0.f};
#pragma unroll
    for (int q = 0; q < 8; ++q) {
        const float4 a = *(const float4*)(p + q * PL + i);
        vv[0] += a.x; vv[1] += a.y; vv[2] += a.z; vv[3] += a.w;
    }
    bf16x4 oh, ol; f16x4 of;
#pragma unroll
    for (int e = 0; e < 4; ++e) {
        const bf16 hi = (bf16)vv[e];
        oh[e] = hi;
        ol[e] = (bf16)(vv[e] - (float)hi);
        of[e] = (f16)vv[e];
    }
    *(bf16x4*)(dh + i) = oh;
    *(bf16x4*)(dl + i) = ol;
    *(f16x4*) (df + i) = of;
}

// ---------------------------------------------------------------------------
// 8-plane f32 reduce + TRANSPOSE -> split bf16 + fp16 (for W_vo^T, W_12^T)
// ---------------------------------------------------------------------------
__global__ __launch_bounds__(256) void reduce8t_k(
    const float* __restrict__ p, bf16* __restrict__ dsth, bf16* __restrict__ dstl,
    f16* __restrict__ dstf)
{
    __shared__ float tf[64][65];
    const long PL = (long)1 << 20;
    const int c0 = blockIdx.x * 64, r0 = blockIdx.y * 64;
    const int t = threadIdx.x;
    const int tr = t >> 4;
    const int tc = (t & 15) * 4;
#pragma unroll
    for (int pp = 0; pp < 4; ++pp) {
        const int r = tr + pp * 16;
        float vv[4] = {0.f, 0.f, 0.f, 0.f};
#pragma unroll
        for (int q = 0; q < 8; ++q) {
            const float4 v = *(const float4*)(p + q * PL + (long)(r0 + r) * 1024 + c0 + tc);
            vv[0] += v.x; vv[1] += v.y; vv[2] += v.z; vv[3] += v.w;
        }
#pragma unroll
        for (int e = 0; e < 4; ++e) tf[r][tc + e] = vv[e];
    }
    __syncthreads();
#pragma unroll
    for (int pp = 0; pp < 4; ++pp) {
        const int c = tr + pp * 16;
        bf16x4 oh, ol; f16x4 of;
#pragma unroll
        for (int e = 0; e < 4; ++e) {
            const float v = tf[tc + e][c];
            const bf16 hi = (bf16)v;
            oh[e] = hi;
            ol[e] = (bf16)(v - (float)hi);
            of[e] = (f16)v;
        }
        *(bf16x4*)(dsth + (long)(c0 + c) * 1024 + r0 + tc) = oh;
        *(bf16x4*)(dstl + (long)(c0 + c) * 1024 + r0 + tc) = ol;
        *(f16x4*) (dstf + (long)(c0 + c) * 1024 + r0 + tc) = of;
    }
}

// ---------------------------------------------------------------------------
// f32 -> split bf16 transpose (weights staged K-contiguous)
// ---------------------------------------------------------------------------
__global__ __launch_bounds__(256) void transpose_k(
    const float* __restrict__ src, bf16* __restrict__ dsth, bf16* __restrict__ dstl,
    int R, int C)
{
    __shared__ bf16 th[64][65];
    __shared__ bf16 tl[64][65];
    const int c0 = blockIdx.x * 64, r0 = blockIdx.y * 64;
    const int t = threadIdx.x;
    const int tr = t >> 4;
    const int tc = (t & 15) * 4;
#pragma unroll
    for (int p = 0; p < 4; ++p) {
        const int r = tr + p * 16;
        const float4 v = *(const float4*)(src + (long)(r0 + r) * C + c0 + tc);
        const float vv[4] = {v.x, v.y, v.z, v.w};
#pragma unroll
        for (int e = 0; e < 4; ++e) {
            const bf16 hi = (bf16)vv[e];
            th[r][tc + e] = hi;
            tl[r][tc + e] = (bf16)(vv[e] - (float)hi);
        }
    }
    __syncthreads();
#pragma unroll
    for (int p = 0; p < 4; ++p) {
        const int c = tr + p * 16;
        bf16x4 oh, ol;
#pragma unroll
        for (int e = 0; e < 4; ++e) { oh[e] = th[tc + e][c]; ol[e] = tl[tc + e][c]; }
        *(bf16x4*)(dsth + (long)(c0 + c) * R + r0 + tc) = oh;
        *(bf16x4*)(dstl + (long)(c0 + c) * R + r0 + tc) = ol;
    }
}

// ---------------------------------------------------------------------------
// wb[d] = sum_h W[d][h] * b[h]   (f32, W is [1024][4096])
// ---------------------------------------------------------------------------
__global__ __launch_bounds__(256) void matvec_wb_k(
    const float* __restrict__ W, const float* __restrict__ b, float* __restrict__ out)
{
    const int d = blockIdx.x;
    const int t = threadIdx.x;
    float s = 0.f;
    for (int h = t * 4; h < HD; h += 1024) {
        const float4 wv = *(const float4*)(W + (long)d * HD + h);
        const float4 bv = *(const float4*)(b + h);
        s += wv.x * bv.x + wv.y * bv.y + wv.z * bv.z + wv.w * bv.w;
    }
#pragma unroll
    for (int o = 32; o; o >>= 1) s += __shfl_xor(s, o);
    __shared__ float red[4];
    if ((t & 63) == 0) red[t >> 6] = s;
    __syncthreads();
    if (t == 0) out[d] = red[0] + red[1] + red[2] + red[3];
}

// ---------------------------------------------------------------------------
// out[j] = sum_h (BtH+BtL)[j][h] * b[h] + add[j]
// ---------------------------------------------------------------------------
__global__ __launch_bounds__(256) void matvec_bt_k(
    const bf16* __restrict__ bth, const bf16* __restrict__ btl,
    const float* __restrict__ b, const float* __restrict__ add,
    float* __restrict__ out)
{
    const int j = blockIdx.x;
    const int t = threadIdx.x;
    float s = 0.f;
    for (int h = t * 4; h < HD; h += 1024) {
        const bf16x4 hx = *(const bf16x4*)(bth + (long)j * HD + h);
        const bf16x4 lx = *(const bf16x4*)(btl + (long)j * HD + h);
        const float4 bv = *(const float4*)(b + h);
        s += ((float)hx[0] + (float)lx[0]) * bv.x + ((float)hx[1] + (float)lx[1]) * bv.y
           + ((float)hx[2] + (float)lx[2]) * bv.z + ((float)hx[3] + (float)lx[3]) * bv.w;
    }
#pragma unroll
    for (int o = 32; o; o >>= 1) s += __shfl_xor(s, o);
    __shared__ float red[4];
    if ((t & 63) == 0) red[t >> 6] = s;
    __syncthreads();
    if (t == 0) out[j] = red[0] + red[1] + red[2] + red[3] + add[j];
}

// ---------------------------------------------------------------------------
// Row softmax with key-side column bias -> fp16 P
// ---------------------------------------------------------------------------
__global__ __launch_bounds__(256) void softmax_k(
    const float* __restrict__ S, const float* __restrict__ v,
    f16* __restrict__ P)
{
    const long row = blockIdx.x;
    const float4* src = (const float4*)(S + (row << 11));
    const float* vr = v + (long)(row >> 11) * SEQ;
    const int t = threadIdx.x;
    float4 a = src[t], b = src[256 + t];
    const float4 va = *(const float4*)(vr + t * 4);
    const float4 vb = *(const float4*)(vr + 1024 + t * 4);
    a.x += va.x; a.y += va.y; a.z += va.z; a.w += va.w;
    b.x += vb.x; b.y += vb.y; b.z += vb.z; b.w += vb.w;
    float m = fmaxf(fmaxf(fmaxf(a.x, a.y), fmaxf(a.z, a.w)),
                    fmaxf(fmaxf(b.x, b.y), fmaxf(b.z, b.w)));
#pragma unroll
    for (int o = 32; o; o >>= 1) m = fmaxf(m, __shfl_xor(m, o));
    __shared__ float red1[4], red2[4];
    const int wv = t >> 6;
    if ((t & 63) == 0) red1[wv] = m;
    __syncthreads();
    m = fmaxf(fmaxf(red1[0], red1[1]), fmaxf(red1[2], red1[3]));

    a.x = expf(a.x - m); a.y = expf(a.y - m); a.z = expf(a.z - m); a.w = expf(a.w - m);
    b.x = expf(b.x - m); b.y = expf(b.y - m); b.z = expf(b.z - m); b.w = expf(b.w - m);
    float s = a.x + a.y + a.z + a.w + b.x + b.y + b.z + b.w;
#pragma unroll
    for (int o = 32; o; o >>= 1) s += __shfl_xor(s, o);
    if ((t & 63) == 0) red2[wv] = s;
    __syncthreads();
    s = red2[0] + red2[1] + red2[2] + red2[3];
    const float inv = 1.0f / s;

    f16x4 o0, o1;
    o0[0] = (f16)(a.x * inv); o0[1] = (f16)(a.y * inv);
    o0[2] = (f16)(a.z * inv); o0[3] = (f16)(a.w * inv);
    o1[0] = (f16)(b.x * inv); o1[1] = (f16)(b.y * inv);
    o1[2] = (f16)(b.z * inv); o1[3] = (f16)(b.w * inv);
    *(f16x4*)(P + (row << 11) + t * 4) = o0;
    *(f16x4*)(P + (row << 11) + 1024 + t * 4) = o1;
}

// ---------------------------------------------------------------------------
// LayerNorm over whole (S,D) sample; residual carried as split bf16 (hi+lo).
// ---------------------------------------------------------------------------
__global__ __launch_bounds__(256) void ln_stats_k(
    const bf16* __restrict__ yh, const bf16* __restrict__ yl,
    const float* __restrict__ r, float2* __restrict__ part)
{
    const int b = blockIdx.y;
    const long base = (long)b * SD + (long)blockIdx.x * (SD / 64);
    float s = 0.f, q = 0.f;
    for (int i = threadIdx.x; i < (SD / 64) / 4; i += 256) {
        const bf16x4 h = *(const bf16x4*)(yh + base + i * 4);
        const bf16x4 l = *(const bf16x4*)(yl + base + i * 4);
        const float4 c = *(const float4*)(r + base + i * 4);
        const float cc[4] = {c.x, c.y, c.z, c.w};
#pragma unroll
        for (int e = 0; e < 4; ++e) {
            const float xx = (float)h[e] + (float)l[e] + cc[e];
            s += xx; q += xx * xx;
        }
    }
#pragma unroll
    for (int o = 32; o; o >>= 1) { s += __shfl_xor(s, o); q += __shfl_xor(q, o); }
    __shared__ float rs[4], rq[4];
    const int wv = threadIdx.x >> 6;
    if ((threadIdx.x & 63) == 0) { rs[wv] = s; rq[wv] = q; }
    __syncthreads();
    if (threadIdx.x == 0)
        part[b * 64 + blockIdx.x] = make_float2(rs[0] + rs[1] + rs[2] + rs[3],
                                                rq[0] + rq[1] + rq[2] + rq[3]);
}

__global__ void ln_fin_k(const float2* __restrict__ part, float2* __restrict__ stats)
{
    const int b = blockIdx.x;
    const float2 p = part[b * 64 + threadIdx.x];
    float s = p.x, q = p.y;
#pragma unroll
    for (int o = 32; o; o >>= 1) { s += __shfl_xor(s, o); q += __shfl_xor(q, o); }
    if (threadIdx.x == 0) {
        const float inv_n = 1.0f / (float)SD;
        const float mean = s * inv_n;
        const float var = fmaxf(q * inv_n - mean * mean, 0.f);
        stats[b] = make_float2(mean, rsqrtf(var + 1e-5f));
    }
}

// ln_apply: one block per row. Writes split bf16 + fp16 (+f32 out) and
// optionally the NEXT layer's key-side bias dot (vb[row] = dot(o, wkbq)).
__global__ __launch_bounds__(256) void ln_apply_k(
    const bf16* __restrict__ yh_in, const bf16* __restrict__ yl_in,
    const float* __restrict__ r,
    const float* __restrict__ w, const float* __restrict__ bb,
    const float2* __restrict__ stats,
    bf16* __restrict__ yh_out, bf16* __restrict__ yl_out, f16* __restrict__ yf16,
    float* __restrict__ fout,
    const float* __restrict__ wkbq, float* __restrict__ vb)
{
    const long i = (long)blockIdx.x * 1024 + threadIdx.x * 4;
    const int smp = (int)(i >> 21);
    const long sd = i & (SD - 1);
    const float2 st = stats[smp];
    const bf16x4 h = *(const bf16x4*)(yh_in + i);
    const bf16x4 l = *(const bf16x4*)(yl_in + i);
    const float4 c = *(const float4*)(r + i);
    const float4 wv = *(const float4*)(w + sd);
    const float4 bv = *(const float4*)(bb + sd);
    const float cc[4] = {c.x, c.y, c.z, c.w};
    const float ww[4] = {wv.x, wv.y, wv.z, wv.w};
    const float bbx[4] = {bv.x, bv.y, bv.z, bv.w};
    float o[4];
#pragma unroll
    for (int e = 0; e < 4; ++e) {
        const float xx = (float)h[e] + (float)l[e] + cc[e];
        o[e] = (xx - st.x) * st.y * ww[e] + bbx[e];
    }
    bf16x4 oh, ol; f16x4 of;
#pragma unroll
    for (int e = 0; e < 4; ++e) {
        oh[e] = (bf16)o[e];
        ol[e] = (bf16)(o[e] - (float)oh[e]);
        of[e] = (f16)o[e];
    }
    *(bf16x4*)(yh_out + i) = oh;
    *(bf16x4*)(yl_out + i) = ol;
    *(f16x4*) (yf16 + i) = of;
    if (fout != nullptr) *(float4*)(fout + i) = *(float4*)o;
    if (vb != nullptr) {
        const int d = threadIdx.x * 4;
        const float4 kv = *(const float4*)(wkbq + d);
        float sdot = o[0] * kv.x + o[1] * kv.y + o[2] * kv.z + o[3] * kv.w;
#pragma unroll
        for (int off = 32; off; off >>= 1) sdot += __shfl_xor(sdot, off);
        __shared__ float red[4];
        if ((threadIdx.x & 63) == 0) red[threadIdx.x >> 6] = sdot;
        __syncthreads();
        if (threadIdx.x == 0) vb[blockIdx.x] = red[0] + red[1] + red[2] + red[3];
    }
}

// ---------------------------------------------------------------------------
extern "C" void kernel_launch(void* const* d_in, const int* in_sizes, int n_in,
                              void* d_out, int out_size, void* d_ws, size_t ws_size,
                              hipStream_t stream)
{
    (void)in_sizes; (void)n_in; (void)out_size; (void)ws_size;

    const int*   x    = (const int*)  d_in[0];
    const float* emb  = (const float*)d_in[1];
    const float* wq   = (const float*)d_in[2];
    const float* bq   = (const float*)d_in[3];
    const float* wk   = (const float*)d_in[4];
    const float* bk   = (const float*)d_in[5];
    const float* wv   = (const float*)d_in[6];
    const float* bv   = (const float*)d_in[7];
    const float* wo   = (const float*)d_in[8];
    const float* bo   = (const float*)d_in[9];
    const float* w1   = (const float*)d_in[10];
    const float* b1   = (const float*)d_in[11];
    const float* w2   = (const float*)d_in[12];
    const float* b2   = (const float*)d_in[13];
    const float* ln1w = (const float*)d_in[14];
    const float* ln1b = (const float*)d_in[15];
    const float* ln2w = (const float*)d_in[16];
    const float* ln2b = (const float*)d_in[17];
    (void)bk;   // cancels in softmax (row-constant)

    // Workspace — peak ~324 MiB (≤384 proven-safe).
    char* ws = (char*)d_ws;
    const size_t MB = (size_t)1 << 20;
    bf16*   ybh   = (bf16*) (ws);                  //  16 MiB residual hi
    bf16*   ybl   = (bf16*) (ws + 16  * MB);       //  16 MiB residual lo
    f16*    yf16  = (f16*)  (ws + 32  * MB);       //  16 MiB residual fp16
    bf16*   S0h   = (bf16*) (ws + 48  * MB);       //   8 MiB weight slot 0 hi
    bf16*   S0l   = (bf16*) (ws + 56  * MB);       //   8 MiB weight slot 0 lo
    bf16*   S1h   = (bf16*) (ws + 64  * MB);       //   8 MiB weight slot 1 hi
    bf16*   S1l   = (bf16*) (ws + 72  * MB);       //   8 MiB weight slot 1 lo
    bf16*   MTh   = (bf16*) (ws + 80  * MB);       //   2 MiB
    bf16*   MTl   = (bf16*) (ws + 82  * MB);       //   2 MiB
    f16*    MTf   = (f16*)  (ws + 84  * MB);       //   2 MiB
    bf16*   VOh   = (bf16*) (ws + 86  * MB);       //   2 MiB
    bf16*   VOl   = (bf16*) (ws + 88  * MB);       //   2 MiB
    f16*    VOf   = (f16*)  (ws + 90  * MB);       //   2 MiB
    bf16*   W12h  = (bf16*) (ws + 92  * MB);       //   2 MiB
    bf16*   W12l  = (bf16*) (ws + 94  * MB);       //   2 MiB
    f16*    W12f  = (f16*)  (ws + 96  * MB);       //   2 MiB
    float*  wkbq2 = (float*)(ws + 98  * MB);                // 2 x 4 KiB
    float*  c_vo  = (float*)(ws + 98  * MB + 0x10000);      // 4 KiB
    float*  c_12  = (float*)(ws + 98  * MB + 0x20000);      // 4 KiB
    float*  vbias = (float*)(ws + 98  * MB + 0x30000);      // 32 KiB
    float2* part  = (float2*)(ws + 98 * MB + 0x40000);
    float2* stats = (float2*)(ws + 98 * MB + 0x50000);
    float*  wtmp8 = (float*)(ws + 100 * MB);       //  32 MiB K-split f32 partials
    bf16*   zh    = (bf16*) (ws + 132 * MB);       //  16 MiB z hi [8192][1024]
    bf16*   zl    = (bf16*) (ws + 148 * MB);       //  16 MiB z lo
    f16*    zf    = (f16*)  (ws + 164 * MB);       //  16 MiB z fp16
    f16*    uTf   = (f16*)  (ws + 180 * MB);       //  16 MiB u^T fp16 [4][1024][2048]
    float*  scf   = (float*)(ws + 196 * MB);       //  64 MiB scores f32 [4][2048][2048]
    f16*    Pf    = (f16*)  (ws + 260 * MB);       //  32 MiB probs fp16
    float*  attout= (float*)(ws + 292 * MB);       //  32 MiB f32 [8192][1024]
    float*  ffnf  = attout;

    const long TSZ = (long)DM * HD;

    // both layers' key-side weight-bias vectors (weight-only, precompute)
    matvec_wb_k<<<1024, 256, 0, stream>>>(wk + 0 * TSZ, bq + 0 * HD, wkbq2);
    matvec_wb_k<<<1024, 256, 0, stream>>>(wk + 1 * TSZ, bq + 1 * HD, wkbq2 + 0x4000 / 4);

    embed_k<<<NB * SEQ, 256, 0, stream>>>(x, emb, ybh, ybl, yf16, wkbq2, vbias);

    for (int l = 0; l < 2; ++l) {
        const float* wkbq_next = wkbq2 + 0x4000 / 4;   // layer-1 vector

        // ============ score path ============
        copy_split_k<<<4096, 256, 0, stream>>>(wq + l * TSZ, S0h, S0l);
        copy_split_k<<<4096, 256, 0, stream>>>(wk + l * TSZ, S1h, S1l);
        // MT = Wk·Wq^T (K-split x8, NP=3, f32 partials)
        gemm3_nt<0, false, 3, 0><<<dim3(8, 8, 8), 256, 0, stream>>>(
            S1h, S1l, S0h, S0l, nullptr, wtmp8, nullptr,
            512, HD, 1024, 512, 512, (long)1 << 20);
        reduce8s_k<<<1024, 256, 0, stream>>>(wtmp8, MTh, MTl, MTf);
        if (l == 0) {
            // strict: z and scores NP=3 bf16-split (double-softmax amplified)
            gemm3_nt<4, false, 3, 0><<<dim3(64, 8, 1), 256, 0, stream>>>(
                ybh, ybl, MTh, MTl, nullptr, zh, zl, DM, DM, DM, 0, 0, 0);
            gemm3_nt<0, false, 3, 0><<<dim3(16, 16, NB), 256, 0, stream>>>(
                zh, zl, ybh, ybl, nullptr, scf, nullptr,
                DM, DM, SEQ, (long)SD, (long)SD, (long)SEQ * SEQ);
        } else {
            // relaxed: fp16 single-pass (feeds output only)
            gemm3_nt<6, false, 1, 1><<<dim3(64, 8, 1), 256, 0, stream>>>(
                (const bf16*)yf16, nullptr, (const bf16*)MTf, nullptr, nullptr,
                zf, nullptr, DM, DM, DM, 0, 0, 0);
            gemm3_nt<0, false, 1, 1><<<dim3(16, 16, NB), 256, 0, stream>>>(
                (const bf16*)zf, nullptr, (const bf16*)yf16, nullptr, nullptr,
                scf, nullptr, DM, DM, SEQ, (long)SD, (long)SD, (long)SEQ * SEQ);
        }
        softmax_k<<<NB * SEQ, 256, 0, stream>>>(scf, vbias, Pf);

        // ============ value path: W_vo = Wv·Wo ============
        copy_split_k<<<4096, 256, 0, stream>>>(wv + l * TSZ, S0h, S0l);
        transpose_k <<<dim3(16, 64), 256, 0, stream>>>(wo + l * TSZ, S1h, S1l, HD, DM);
        matvec_bt_k<<<1024, 256, 0, stream>>>(S1h, S1l, bv + l * HD, bo + l * DM, c_vo);
        if (l == 0)
            gemm3_nt<0, false, 3, 0><<<dim3(8, 8, 8), 256, 0, stream>>>(
                S0h, S0l, S1h, S1l, nullptr, wtmp8, nullptr,
                512, HD, 1024, 512, 512, (long)1 << 20);
        else
            gemm3_nt<0, false, 1, 0><<<dim3(8, 8, 8), 256, 0, stream>>>(
                S0h, nullptr, S1h, nullptr, nullptr, wtmp8, nullptr,
                512, HD, 1024, 512, 512, (long)1 << 20);
        reduce8t_k<<<dim3(16, 16), 256, 0, stream>>>(wtmp8, VOh, VOl, VOf);
        // u^T = (y·W_vo)^T -> fp16 [4][1024][2048]
        if (l == 0)   // accurate compute (NP=3), fp16 storage
            gemm3_nt<7, false, 3, 0><<<dim3(16, 8, NB), 256, 0, stream>>>(
                ybh, ybl, VOh, VOl, nullptr, uTf, nullptr,
                DM, DM, SEQ, (long)SD, 0, (long)DM * SEQ);
        else
            gemm3_nt<7, false, 1, 1><<<dim3(16, 8, NB), 256, 0, stream>>>(
                (const bf16*)yf16, nullptr, (const bf16*)VOf, nullptr, nullptr,
                uTf, nullptr, DM, DM, SEQ, (long)SD, 0, (long)DM * SEQ);
        // attout = P·u + c_vo (fp16 NP=1 both layers)
        gemm3_nt<0, true, 1, 1><<<dim3(16, 8, NB), 256, 0, stream>>>(
            (const bf16*)Pf, nullptr, (const bf16*)uTf, nullptr, c_vo, attout, nullptr,
            SEQ, SEQ, DM, (long)SEQ * SEQ, (long)DM * SEQ, (long)SEQ * DM);
        // LN1(y + attout)
        ln_stats_k<<<dim3(64, NB), 256, 0, stream>>>(ybh, ybl, attout, part);
        ln_fin_k  <<<NB, 64, 0, stream>>>(part, stats);
        ln_apply_k<<<8192, 256, 0, stream>>>(ybh, ybl, attout,
                                             ln1w + (long)l * SD, ln1b + (long)l * SD,
                                             stats, ybh, ybl, yf16, nullptr,
                                             nullptr, nullptr);

        // ============ FFN path: W_12 = W1·W2 (exact collapse) ============
        copy_split_k<<<4096, 256, 0, stream>>>(w1 + l * TSZ, S0h, S0l);
        transpose_k <<<dim3(16, 64), 256, 0, stream>>>(w2 + l * TSZ, S1h, S1l, HD, DM);
        matvec_bt_k<<<1024, 256, 0, stream>>>(S1h, S1l, b1 + l * HD, b2 + l * DM, c_12);
        if (l == 0)
            gemm3_nt<0, false, 3, 0><<<dim3(8, 8, 8), 256, 0, stream>>>(
                S0h, S0l, S1h, S1l, nullptr, wtmp8, nullptr,
                512, HD, 1024, 512, 512, (long)1 << 20);
        else
            gemm3_nt<0, false, 1, 0><<<dim3(8, 8, 8), 256, 0, stream>>>(
                S0h, nullptr, S1h, nullptr, nullptr, wtmp8, nullptr,
                512, HD, 1024, 512, 512, (long)1 << 20);
        reduce8t_k<<<dim3(16, 16), 256, 0, stream>>>(wtmp8, W12h, W12l, W12f);
        // ffn = gelu(y·W_12 + c_12) (fp16 NP=1)
        gemm3_nt<1, true, 1, 1><<<dim3(64, 8, 1), 256, 0, stream>>>(
            (const bf16*)yf16, nullptr, (const bf16*)W12f, nullptr, c_12,
            ffnf, nullptr, DM, DM, DM, 0, 0, 0);
        // LN2; layer-0 apply also emits next layer's vbias; layer-1 writes d_out
        float* fdst = (l == 1) ? (float*)d_out : nullptr;
        ln_stats_k<<<dim3(64, NB), 256, 0, stream>>>(ybh, ybl, ffnf, part);
        ln_fin_k  <<<NB, 64, 0, stream>>>(part, stats);
        ln_apply_k<<<8192, 256, 0, stream>>>(ybh, ybl, ffnf,
                                             ln2w + (long)l * SD, ln2b + (long)l * SD,
                                             stats, ybh, ybl, yf16, fdst,
                                             (l == 0) ? wkbq_next : nullptr,
                                             (l == 0) ? vbias : nullptr);
    }
}